// Round 9
// baseline (1423.148 us; speedup 1.0000x reference)
//
#include <hip/hip_runtime.h>
#include <stdint.h>

#define NN 8192
#define DD 128
#define ALPHA 0.7f
#define BETA 0.3f
#define LAM 0.1f
#define QSCALE 0.08838834764831845f  // 1/sqrt(128)
#define DELTA 3e-5f      // L2 band: 3-term sim error ~1.5e-5
#define DELTA_L1 9e-3f   // L1 band: >= hi-only sim hard bound 7.85e-3
#define FLAGCAP 262144
#define FLAG2CAP 1048576

typedef __attribute__((ext_vector_type(8))) short short8;
typedef __attribute__((ext_vector_type(4))) float f32x4;
typedef unsigned short ush;

__device__ __forceinline__ ush f2bf(float f){
  union { float f; unsigned u; } v; v.f = f;
  return (ush)((v.u + 0x7FFFu + ((v.u >> 16) & 1u)) >> 16);
}
__device__ __forceinline__ float bf2f(ush s){
  union { unsigned u; float f; } v; v.u = ((unsigned)s) << 16; return v.f;
}

// identical scalar QK dot used by BOTH k_fix branches (L1 mode) so that the
// sparse add and any later refine subtract use the exact same s.
__device__ __forceinline__ float qkdot(const ush* __restrict__ Qh,
                                       const ush* __restrict__ Kh,
                                       int i, int j, int lane){
  float q0 = bf2f(Qh[i*DD + lane]),      k0 = bf2f(Kh[j*DD + lane]);
  float q1 = bf2f(Qh[i*DD + 64 + lane]), k1 = bf2f(Kh[j*DD + 64 + lane]);
  float s = q0*k0 + q1*k1;
  #pragma unroll
  for (int m = 32; m; m >>= 1) s += __shfl_xor(s, m, 64);
  return s;
}

// ---------------- one-time init: adjacency pack | weight transposes ----------------
__global__ void k_init(const float* __restrict__ adj, unsigned* __restrict__ adjw,
                       const float* __restrict__ wq, const float* __restrict__ wk,
                       const float* __restrict__ wv, const float* __restrict__ g1w,
                       const float* __restrict__ gcw,
                       ush* __restrict__ qkvTh, ush* __restrict__ qkvTl,
                       ush* __restrict__ g1wTh, ush* __restrict__ g1wTl,
                       ush* __restrict__ gcwTh, ush* __restrict__ gcwTl){
  if (blockIdx.x < NN){
    int i = blockIdx.x, wave = threadIdx.x >> 6, lane = threadIdx.x & 63;
    for (int seg = wave; seg < 128; seg += 4){
      int j = seg*64 + lane;
      unsigned long long bm = __ballot(adj[(size_t)i*NN + j] != 0.0f);
      if (lane == 0)  adjw[i*256 + seg*2]     = (unsigned)bm;
      if (lane == 32) adjw[i*256 + seg*2 + 1] = (unsigned)(bm >> 32);
    }
    return;
  }
  int idx = (blockIdx.x - NN)*256 + threadIdx.x;
  const float* src; ush *dh, *dl; int K, Nout, li;
  if      (idx <  16384){ src=wq;        dh=qkvTh;        dl=qkvTl;        K=128; Nout=128; li=idx; }
  else if (idx <  32768){ src=wk;        dh=qkvTh+16384;  dl=qkvTl+16384;  K=128; Nout=128; li=idx-16384; }
  else if (idx <  49152){ src=wv;        dh=qkvTh+32768;  dl=qkvTl+32768;  K=128; Nout=128; li=idx-32768; }
  else if (idx < 180224){ src=g1w;       dh=g1wTh;        dl=g1wTl;        K=512; Nout=256; li=idx-49152; }
  else if (idx < 196608){ src=gcw;       dh=gcwTh;        dl=gcwTl;        K=128; Nout=128; li=idx-180224; }
  else if (idx < 212992){ src=gcw+16384; dh=gcwTh+16384;  dl=gcwTl+16384;  K=128; Nout=128; li=idx-196608; }
  else return;
  int k = li / Nout, n = li - k*Nout;
  float v = src[li];
  ush h = f2bf(v);
  dh[n*K + k] = h;
  dl[n*K + k] = f2bf(v - bf2f(h));
}

// ---------------- merged per-layer prep: norm | transsplit | qkv (block-range) ----------------
__global__ void k_prep(const float* __restrict__ E, double* __restrict__ nrm64,
                       ush* __restrict__ Enh, ush* __restrict__ Enl,
                       ush* __restrict__ EhiT, ush* __restrict__ EloT,
                       const ush* __restrict__ BtH, const ush* __restrict__ BtL,
                       const float* __restrict__ bq, const float* __restrict__ bk,
                       const float* __restrict__ bv,
                       ush* __restrict__ Qh, ush* __restrict__ Kh,
                       ush* __restrict__ VhT, ush* __restrict__ VloT){
  __shared__ float t[64][65];
  __shared__ float sV[128*33];
  int bid = blockIdx.x, tid = threadIdx.x;
  if (bid < 2048){
    // ---- norm: 4 rows/block ----
    int i = bid*4 + (tid >> 6);
    int l = tid & 63;
    float v0 = E[i*DD + l], v1 = E[i*DD + 64 + l];
    double ss = (double)v0*(double)v0 + (double)v1*(double)v1;
    #pragma unroll
    for (int m = 32; m; m >>= 1) ss += __shfl_xor(ss, m, 64);
    double nr = sqrt(ss); if (nr < 1e-8) nr = 1e-8;
    float inv = (float)(1.0 / nr);
    float n0 = v0*inv, n1 = v1*inv;
    ush h0 = f2bf(n0), h1 = f2bf(n1);
    Enh[i*DD + l] = h0;       Enh[i*DD + 64 + l] = h1;
    Enl[i*DD + l] = f2bf(n0 - bf2f(h0));
    Enl[i*DD + 64 + l] = f2bf(n1 - bf2f(h1));
    if (l == 0) nrm64[i] = nr;
  } else if (bid < 2304){
    // ---- transsplit: fp32 [8192,128] -> hi/lo bf16 T [128,8192] ----
    int lin = bid - 2048;
    int r0 = (lin >> 1) * 64, c0 = (lin & 1) * 64;
    for (int idx = tid; idx < 4096; idx += 256){
      int r = idx >> 6, c = idx & 63;
      t[r][c] = E[(r0 + r)*DD + c0 + c];
    }
    __syncthreads();
    for (int idx = tid; idx < 4096; idx += 256){
      int c = idx >> 6, r = idx & 63;
      float v = t[r][c];
      ush h = f2bf(v);
      EhiT[(size_t)(c0 + c)*NN + r0 + r] = h;
      EloT[(size_t)(c0 + c)*NN + r0 + r] = f2bf(v - bf2f(h));
    }
  } else {
    // ---- qkv: fused Q/K/V projection; V written transposed+split via LDS ----
    int lane = tid & 63, wave = tid >> 6;
    int l15 = lane & 15, quad = lane >> 4;
    int rowblk = (bid - 2304) * 32;
    int row16 = rowblk + (wave >> 1)*16;
    int nf0 = (wave & 1)*12;
    f32x4 acc[12];
    #pragma unroll
    for (int i = 0; i < 12; i++){ f32x4 z = {0.f,0.f,0.f,0.f}; acc[i] = z; }
    #pragma unroll
    for (int kk = 0; kk < 4; kk++){
      const float* ap = &E[(row16 + l15)*DD + kk*32 + quad*8];
      short8 ah, al;
      #pragma unroll
      for (int j = 0; j < 8; j++){
        float v = ap[j];
        ush h = f2bf(v);
        ah[j] = (short)h; al[j] = (short)f2bf(v - bf2f(h));
      }
      #pragma unroll
      for (int i = 0; i < 12; i++){
        int bo = ((nf0 + i)*16 + l15)*DD + kk*32 + quad*8;
        short8 bh = *(const short8*)&BtH[bo];
        short8 bl = *(const short8*)&BtL[bo];
        acc[i] = __builtin_amdgcn_mfma_f32_16x16x32_bf16(ah, bh, acc[i], 0, 0, 0);
        acc[i] = __builtin_amdgcn_mfma_f32_16x16x32_bf16(al, bh, acc[i], 0, 0, 0);
        acc[i] = __builtin_amdgcn_mfma_f32_16x16x32_bf16(ah, bl, acc[i], 0, 0, 0);
      }
    }
    #pragma unroll
    for (int i = 0; i < 12; i++){
      int nfg = nf0 + i;
      int grp = nfg >> 3;
      int col = (nfg & 7)*16 + l15;
      float b = (grp == 0) ? bq[col] : (grp == 1) ? bk[col] : bv[col];
      #pragma unroll
      for (int r = 0; r < 4; r++){
        int row = row16 + quad*4 + r;
        float v = acc[i][r] + b;
        if (grp == 0)      Qh[row*DD + col] = f2bf(v * QSCALE);
        else if (grp == 1) Kh[row*DD + col] = f2bf(v);
        else               sV[col*33 + (row - rowblk)] = v;
      }
    }
    __syncthreads();
    int feat = tid >> 1, rh = (tid & 1)*16;
    ush hh[16], ll[16];
    #pragma unroll
    for (int j = 0; j < 16; j++){
      float v = sV[feat*33 + rh + j];
      ush h = f2bf(v);
      hh[j] = h; ll[j] = f2bf(v - bf2f(h));
    }
    size_t go = (size_t)feat*NN + rowblk + rh;
    *(uint4*)&VhT [go]     = *(const uint4*)&hh[0];
    *(uint4*)&VhT [go + 8] = *(const uint4*)&hh[8];
    *(uint4*)&VloT[go]     = *(const uint4*)&ll[0];
    *(uint4*)&VloT[go + 8] = *(const uint4*)&ll[8];
  }
}

// ---------------- partial-buffer reduction (combined <- sum of 8 splits) ----------------
__global__ void k_reduce(const float4* __restrict__ NsumP, const float4* __restrict__ BsumP,
                         const float* __restrict__ cntNP, const float* __restrict__ denBP,
                         float4* __restrict__ Nsum, float4* __restrict__ Bsum,
                         float* __restrict__ cntN, float* __restrict__ denB, int doB){
  const int NE4 = NN*DD/4;
  int idx = blockIdx.x*256 + threadIdx.x;
  if (idx < NE4){
    float4 a = NsumP[idx];
    #pragma unroll
    for (int s = 1; s < 8; s++){
      float4 u = NsumP[(size_t)s*NE4 + idx];
      a.x += u.x; a.y += u.y; a.z += u.z; a.w += u.w;
    }
    Nsum[idx] = a;
    if (doB){
      float4 b = BsumP[idx];
      #pragma unroll
      for (int s = 1; s < 8; s++){
        float4 u = BsumP[(size_t)s*NE4 + idx];
        b.x += u.x; b.y += u.y; b.z += u.z; b.w += u.w;
      }
      Bsum[idx] = b;
    }
  } else if (idx < NE4 + NN){
    int r = idx - NE4;
    float c = 0.f;
    #pragma unroll
    for (int s = 0; s < 8; s++) c += cntNP[s*NN + r];
    cntN[r] = c;
    if (doB){
      float d2 = 0.f;
      #pragma unroll
      for (int s = 0; s < 8; s++) d2 += denBP[s*NN + r];
      denB[r] = d2;
    }
  }
}

// ---------------- fused MLP: g1 GEMM -> (LDS h) -> gate/fusion/gc GEMM ----------------
__global__ void k_mlp(const float* __restrict__ E, const float* __restrict__ P,
                      const float* __restrict__ B, const float* __restrict__ N,
                      const float* __restrict__ cntP, const float* __restrict__ cntN,
                      const float* __restrict__ denB,
                      const ush* __restrict__ g1Th, const ush* __restrict__ g1Tl,
                      const float* __restrict__ g1b,
                      const float* __restrict__ g2w, const float* __restrict__ g2b,
                      const ush* __restrict__ gcTh, const ush* __restrict__ gcTl,
                      const float* __restrict__ gcb,
                      const float* __restrict__ prevC, const float* __restrict__ lwv,
                      int dofinal, float* __restrict__ out){
  __shared__ float sH[16*260];
  int tid = threadIdx.x, lane = tid & 63, wave = tid >> 6;
  int l15 = lane & 15, quad = lane >> 4;
  int row16 = blockIdx.x*16;
  int row = row16 + l15;
  float cp = cntP[row], cn = cntN[row], dn = denB[row];
  // ---- phase 1: g1 (4-nf waves over 256 cols) ----
  {
    int nf0 = wave*4;
    float rs[4] = {1.f, 1.f/fmaxf(cp,1.f), (dn > 0.5f) ? (1.f/dn) : 0.f, LAM/fmaxf(cn,1.f)};
    const float* bases[4] = {E, P, B, N};
    f32x4 acc[4];
    #pragma unroll
    for (int nf = 0; nf < 4; nf++){ f32x4 z = {0.f,0.f,0.f,0.f}; acc[nf] = z; }
    #pragma unroll
    for (int kk = 0; kk < 16; kk++){
      const float* ap = &bases[kk>>2][row*DD + (kk&3)*32 + quad*8];
      float sc = rs[kk>>2];
      short8 ah, al;
      #pragma unroll
      for (int j = 0; j < 8; j++){
        float v = ap[j] * sc;
        ush h = f2bf(v);
        ah[j] = (short)h; al[j] = (short)f2bf(v - bf2f(h));
      }
      #pragma unroll
      for (int nf = 0; nf < 4; nf++){
        int bo = ((nf0 + nf)*16 + l15)*512 + kk*32 + quad*8;
        short8 bh = *(const short8*)&g1Th[bo];
        short8 bl = *(const short8*)&g1Tl[bo];
        acc[nf] = __builtin_amdgcn_mfma_f32_16x16x32_bf16(ah, bh, acc[nf], 0, 0, 0);
        acc[nf] = __builtin_amdgcn_mfma_f32_16x16x32_bf16(al, bh, acc[nf], 0, 0, 0);
        acc[nf] = __builtin_amdgcn_mfma_f32_16x16x32_bf16(ah, bl, acc[nf], 0, 0, 0);
      }
    }
    #pragma unroll
    for (int nf = 0; nf < 4; nf++){
      int col = (nf0 + nf)*16 + l15;
      float b = g1b[col];
      #pragma unroll
      for (int r = 0; r < 4; r++)
        sH[(quad*4 + r)*260 + col] = fmaxf(acc[nf][r] + b, 0.f);
    }
  }
  __syncthreads();
  // ---- phase 2: gate + fusion + gc GEMM (2-nf waves over 128 cols) ----
  {
    int nf0 = wave*2;
    float l0=0,l1=0,l2=0,l3=0;
    #pragma unroll
    for (int i = 0; i < 16; i++){
      float4 hv = *(const float4*)&sH[l15*260 + quad*64 + i*4];
      float hvv[4] = {hv.x, hv.y, hv.z, hv.w};
      #pragma unroll
      for (int j = 0; j < 4; j++){
        float4 w4 = *(const float4*)&g2w[(quad*64 + i*4 + j)*4];
        l0 = fmaf(hvv[j], w4.x, l0); l1 = fmaf(hvv[j], w4.y, l1);
        l2 = fmaf(hvv[j], w4.z, l2); l3 = fmaf(hvv[j], w4.w, l3);
      }
    }
    l0 += __shfl_xor(l0,16,64); l0 += __shfl_xor(l0,32,64);
    l1 += __shfl_xor(l1,16,64); l1 += __shfl_xor(l1,32,64);
    l2 += __shfl_xor(l2,16,64); l2 += __shfl_xor(l2,32,64);
    l3 += __shfl_xor(l3,16,64); l3 += __shfl_xor(l3,32,64);
    l0 += g2b[0]; l1 += g2b[1]; l2 += g2b[2]; l3 += g2b[3];
    float mx = fmaxf(fmaxf(l0,l1), fmaxf(l2,l3));
    float e0 = __expf(l0-mx), e1 = __expf(l1-mx), e2 = __expf(l2-mx), e3 = __expf(l3-mx);
    float inv = 1.f/(e0+e1+e2+e3);
    float g0 = e0*inv, g1v = e1*inv, g2v = e2*inv, g3 = e3*inv;
    bool any = (cp + cn > 0.5f) || (dn > 0.5f);
    float pscl = g1v/fmaxf(cp,1.f);
    float bscl = (dn > 0.5f) ? (g2v/dn) : 0.f;
    float nscl = LAM*g3/fmaxf(cn,1.f);
    f32x4 acc[2];
    #pragma unroll
    for (int nf = 0; nf < 2; nf++){ f32x4 z = {0.f,0.f,0.f,0.f}; acc[nf] = z; }
    #pragma unroll
    for (int kk = 0; kk < 4; kk++){
      int koff = row*DD + kk*32 + quad*8;
      short8 ah, al;
      #pragma unroll
      for (int j = 0; j < 8; j++){
        float ev = E[koff + j];
        float v = any ? (g0*ev + pscl*P[koff+j] + bscl*B[koff+j] + nscl*N[koff+j]) : ev;
        ush h = f2bf(v);
        ah[j] = (short)h; al[j] = (short)f2bf(v - bf2f(h));
      }
      #pragma unroll
      for (int nf = 0; nf < 2; nf++){
        int bo = ((nf0 + nf)*16 + l15)*DD + kk*32 + quad*8;
        short8 bh = *(const short8*)&gcTh[bo];
        short8 bl = *(const short8*)&gcTl[bo];
        acc[nf] = __builtin_amdgcn_mfma_f32_16x16x32_bf16(ah, bh, acc[nf], 0, 0, 0);
        acc[nf] = __builtin_amdgcn_mfma_f32_16x16x32_bf16(al, bh, acc[nf], 0, 0, 0);
        acc[nf] = __builtin_amdgcn_mfma_f32_16x16x32_bf16(ah, bl, acc[nf], 0, 0, 0);
      }
    }
    float we0 = 0.5f, we1 = 0.5f;
    if (dofinal){
      float a0 = lwv[0], a1 = lwv[1];
      float mw = fmaxf(a0, a1);
      float x0 = __expf(a0-mw), x1 = __expf(a1-mw);
      float iv = 1.f/(x0+x1);
      we0 = x0*iv; we1 = x1*iv;
    }
    #pragma unroll
    for (int nf = 0; nf < 2; nf++){
      int col = (nf0 + nf)*16 + l15;
      float b = gcb[col];
      #pragma unroll
      for (int r = 0; r < 4; r++){
        int rr = row16 + quad*4 + r;
        float val = fmaxf(acc[nf][r] + b, 0.f);
        if (dofinal) val = we0*prevC[rr*DD + col] + we1*val;
        out[rr*DD + col] = val;
      }
    }
  }
}

// ---------------- fused sim/classify/aggregate (R7 per-wave schedule FROZEN) ----------------
// R16: dense accumulators de-atomicized -> per-split PRIVATE partial buffers with
// plain stores (one writer per line; no RMW ping-pong; no zeroing needed). This
// makes CSPLIT=8 safe (R8/R10 failure mechanism was cross-XCD atomic migration).
// Grid 1024, split = blockIdx&7 = XCD (round-robin) -> per-XCD read set ~1.3MB.
// LDS slim: FSTRIDE/MSTRIDE 80->40 (lo halves unused since R15) -> L2 LDS 51.7KB
// -> 3 blocks/CU; L1 ~24KB -> grid-capped 4 blocks/CU. launch_bounds (256,3).
#define BM 64
#define BN 32
#define CSPLIT 8
#define CCHUNK (NN/CSPLIT)
#define NTILES (CCHUNK/BN)
#define RSTRIDE 136
#define FSTRIDE 40
#define MSTRIDE 40

template<int DENSEB>
__launch_bounds__(256, 3)
__global__ void k_fused(const unsigned* __restrict__ adjw,
    const ush* __restrict__ Enh, const ush* __restrict__ Enl,
    const ush* __restrict__ Qh,  const ush* __restrict__ Kh,
    const ush* __restrict__ EhiT, const ush* __restrict__ EloT,
    const ush* __restrict__ VhT,  const ush* __restrict__ VloT,
    float* __restrict__ NsumP, float* __restrict__ BsumP,
    float* __restrict__ cntNP, float* __restrict__ denBP,
    int* __restrict__ flagCnt, float4* __restrict__ flags,
    int* __restrict__ flag2Cnt, float4* __restrict__ flags2)
{
  __shared__ __attribute__((aligned(16))) ush sEnh[32*RSTRIDE];
  __shared__ __attribute__((aligned(16))) ush sEnl[DENSEB ? 32*RSTRIDE : 16];
  __shared__ __attribute__((aligned(16))) ush sKh [DENSEB ? 32*RSTRIDE : 16];
  __shared__ __attribute__((aligned(16))) ush sE2 [128*FSTRIDE];
  __shared__ __attribute__((aligned(16))) ush sV2 [DENSEB ? 128*FSTRIDE : 16];
  __shared__ __attribute__((aligned(16))) ush sM  [4][16*MSTRIDE];

  const float del = DENSEB ? DELTA : DELTA_L1;
  int tid = threadIdx.x, lane = tid & 63, wave = tid >> 6;
  int l15 = lane & 15, quad = lane >> 4;
  int rowblk = blockIdx.x >> 3, split = blockIdx.x & 7;  // split == XCD id
  int row0 = rowblk * BM + wave * 16;
  int col0 = split * CCHUNK;

  short8 bEnh[4], bEnl[4], bQ[4];
  #pragma unroll
  for (int kf = 0; kf < 4; kf++){
    int go = (row0 + l15)*DD + kf*32 + quad*8;
    bEnh[kf] = *(const short8*)&Enh[go];
    if (DENSEB){
      bEnl[kf] = *(const short8*)&Enl[go];
      bQ[kf] = *(const short8*)&Qh[go];
    }
  }

  f32x4 accN[8], accB[DENSEB ? 8 : 1];
  #pragma unroll
  for (int nf = 0; nf < 8; nf++){ f32x4 z = {0.f,0.f,0.f,0.f}; accN[nf]=z; }
  if (DENSEB){
    #pragma unroll
    for (int nf = 0; nf < 8; nf++){ f32x4 z = {0.f,0.f,0.f,0.f}; accB[nf]=z; }
  }
  float cnL = 0.f, dbL = 0.f;

  int f0 = tid >> 2,        n0 = (tid & 3)*8;
  int f1 = (tid+256) >> 2,  n1 = ((tid+256) & 3)*8;
  uint4 pEh0, pEh1, pVh0, pVh1;
  {
    size_t g0 = (size_t)f0*NN + col0 + n0, g1 = (size_t)f1*NN + col0 + n1;
    pEh0 = *(const uint4*)&EhiT[g0]; pEh1 = *(const uint4*)&EhiT[g1];
    if (DENSEB){
      pVh0 = *(const uint4*)&VhT [g0]; pVh1 = *(const uint4*)&VhT [g1];
    }
  }
  int rr0 = tid >> 4,       ro0 = (tid & 15)*8;
  int rr1 = (tid+256) >> 4, ro1 = ((tid+256) & 15)*8;

  for (int t = 0; t < NTILES; t++){
    int c0 = col0 + t*BN;
    __syncthreads();
    *(uint4*)&sE2[f0*FSTRIDE + n0] = pEh0;  *(uint4*)&sE2[f1*FSTRIDE + n1] = pEh1;
    if (DENSEB){
      *(uint4*)&sV2[f0*FSTRIDE + n0] = pVh0;  *(uint4*)&sV2[f1*FSTRIDE + n1] = pVh1;
    }
    {
      uint4 a0 = *(const uint4*)&Enh[(c0 + rr0)*DD + ro0];
      uint4 a1 = *(const uint4*)&Enh[(c0 + rr1)*DD + ro1];
      *(uint4*)&sEnh[rr0*RSTRIDE + ro0] = a0;  *(uint4*)&sEnh[rr1*RSTRIDE + ro1] = a1;
      if (DENSEB){
        uint4 b0 = *(const uint4*)&Enl[(c0 + rr0)*DD + ro0];
        uint4 b1 = *(const uint4*)&Enl[(c0 + rr1)*DD + ro1];
        uint4 k0 = *(const uint4*)&Kh [(c0 + rr0)*DD + ro0];
        uint4 k1 = *(const uint4*)&Kh [(c0 + rr1)*DD + ro1];
        *(uint4*)&sEnl[rr0*RSTRIDE + ro0] = b0;  *(uint4*)&sEnl[rr1*RSTRIDE + ro1] = b1;
        *(uint4*)&sKh [rr0*RSTRIDE + ro0] = k0;  *(uint4*)&sKh [rr1*RSTRIDE + ro1] = k1;
      }
    }
    __syncthreads();
    if (t + 1 < NTILES){
      int c1 = c0 + BN;
      size_t g0 = (size_t)f0*NN + c1 + n0, g1 = (size_t)f1*NN + c1 + n1;
      pEh0 = *(const uint4*)&EhiT[g0]; pEh1 = *(const uint4*)&EhiT[g1];
      if (DENSEB){
        pVh0 = *(const uint4*)&VhT [g0]; pVh1 = *(const uint4*)&VhT [g1];
      }
    }
    unsigned aw = adjw[(row0 + l15)*256 + (c0 >> 5)];

    f32x4 simT[2], svT[2];
    { f32x4 z = {0.f,0.f,0.f,0.f}; simT[0]=z; simT[1]=z; svT[0]=z; svT[1]=z; }
    #pragma unroll
    for (int f = 0; f < 2; f++){
      #pragma unroll
      for (int kf = 0; kf < 4; kf++){
        int la = (f*16 + l15)*RSTRIDE + kf*32 + quad*8;
        short8 ch = *(const short8*)&sEnh[la];
        simT[f] = __builtin_amdgcn_mfma_f32_16x16x32_bf16(ch, bEnh[kf], simT[f],0,0,0);
        if (DENSEB){
          short8 cl = *(const short8*)&sEnl[la];
          short8 ck = *(const short8*)&sKh [la];
          simT[f] = __builtin_amdgcn_mfma_f32_16x16x32_bf16(cl, bEnh[kf], simT[f],0,0,0);
          simT[f] = __builtin_amdgcn_mfma_f32_16x16x32_bf16(ch, bEnl[kf], simT[f],0,0,0);
          svT [f] = __builtin_amdgcn_mfma_f32_16x16x32_bf16(ck, bQ  [kf], svT [f],0,0,0);
        }
      }
    }
    ushort4 ehv[2];
    unsigned flagb = 0, spb = 0;
    #pragma unroll
    for (int f = 0; f < 2; f++){
      ush vn2[4], veh[4];
      #pragma unroll
      for (int r = 0; r < 4; r++){
        int cbit = f*16 + quad*4 + r;
        bool nbr = (aw >> cbit) & 1u;
        float c = simT[f][r];
        bool pos = nbr && (c >= ALPHA);
        bool neg = nbr && (c <= BETA);
        bool bnd = nbr && !pos && !neg;
        vn2[r] = neg ? (ush)0x3F80 : (ush)0;
        cnL += neg ? 1.f : 0.f;
        if (DENSEB){
          float e = bnd ? __expf(svT[f][r]) : 0.f;
          veh[r] = f2bf(e);
          dbL += e;
        }
        if (nbr && (fabsf(c - ALPHA) < del || fabsf(c - BETA) < del))
          flagb |= 1u << (f*4 + r);
        if (pos || (!DENSEB && bnd))
          spb |= 1u << (f*4 + r);
      }
      int mb = l15*MSTRIDE + f*16 + quad*4;
      *(ushort4*)&sM[wave][mb] = make_ushort4(vn2[0],vn2[1],vn2[2],vn2[3]);
      if (DENSEB)
        ehv[f] = make_ushort4(veh[0],veh[1],veh[2],veh[3]);
    }
    if (__ballot((flagb | spb) != 0)){
      #pragma unroll
      for (int f = 0; f < 2; f++){
        #pragma unroll
        for (int r = 0; r < 4; r++){
          int bit = f*4 + r;
          bool fl = (flagb >> bit) & 1u;
          unsigned long long bm = __ballot(fl);
          if (bm){
            int leader = __ffsll((long long)bm) - 1;
            int base = 0;
            if (lane == leader) base = atomicAdd(flagCnt, __popcll(bm));
            base = __shfl(base, leader, 64);
            if (fl){
              int id = base + __popcll(bm & ((1ull << lane) - 1ull));
              if (id < FLAGCAP){
                float4 rec;
                rec.x = __int_as_float(row0 + l15);
                rec.y = __int_as_float(c0 + f*16 + quad*4 + r);
                rec.z = simT[f][r];
                rec.w = DENSEB ? svT[f][r] : 0.f;
                flags[id] = rec;
              }
            }
          }
          bool f2 = (spb >> bit) & 1u;
          unsigned long long bm2 = __ballot(f2);
          if (bm2){
            int leader = __ffsll((long long)bm2) - 1;
            int base = 0;
            if (lane == leader) base = atomicAdd(flag2Cnt, __popcll(bm2));
            base = __shfl(base, leader, 64);
            if (f2){
              int id = base + __popcll(bm2 & ((1ull << lane) - 1ull));
              if (id < FLAG2CAP){
                float c = simT[f][r];
                int j = c0 + f*16 + quad*4 + r;
                int cls = (c >= ALPHA) ? 0 : 1;
                float4 rec;
                rec.x = __int_as_float(row0 + l15);
                rec.y = __int_as_float(j | (cls << 16));
                rec.z = c;
                rec.w = DENSEB ? svT[f][r] : 0.f;
                flags2[id] = rec;
              }
            }
          }
        }
      }
    }
    {
      short8 mNeg = *(const short8*)&sM[wave][l15*MSTRIDE + quad*8];
      #pragma unroll
      for (int nf = 0; nf < 8; nf++){
        int so = (nf*16 + l15)*FSTRIDE + quad*8;
        short8 eth = *(const short8*)&sE2[so];
        accN[nf] = __builtin_amdgcn_mfma_f32_16x16x32_bf16(mNeg, eth, accN[nf],0,0,0);
      }
    }
    if (DENSEB){
      int mb0 = l15*MSTRIDE + quad*4;
      *(ushort4*)&sM[wave][mb0]      = ehv[0];
      *(ushort4*)&sM[wave][mb0 + 16] = ehv[1];
      short8 mEh = *(const short8*)&sM[wave][l15*MSTRIDE + quad*8];
      #pragma unroll
      for (int nf = 0; nf < 8; nf++){
        int so = (nf*16 + l15)*FSTRIDE + quad*8;
        short8 vth = *(const short8*)&sV2[so];
        accB[nf] = __builtin_amdgcn_mfma_f32_16x16x32_bf16(mEh, vth, accB[nf],0,0,0);
      }
    }
  }
  // ---- epilogue: PLAIN STORES to this split's private partial buffers ----
  float* Np = NsumP + (size_t)split*(NN*DD);
  float* Bp = BsumP + (size_t)split*(NN*DD);
  #pragma unroll
  for (int nf = 0; nf < 8; nf++){
    int col = nf*16 + l15;
    #pragma unroll
    for (int r = 0; r < 4; r++){
      int row = row0 + quad*4 + r;
      Np[row*DD + col] = accN[nf][r];
      if (DENSEB) Bp[row*DD + col] = accB[nf][r];
    }
  }
  cnL += __shfl_xor(cnL, 16, 64); cnL += __shfl_xor(cnL, 32, 64);
  if (DENSEB){ dbL += __shfl_xor(dbL, 16, 64); dbL += __shfl_xor(dbL, 32, 64); }
  if (quad == 0){
    cntNP[split*NN + row0 + l15] = cnL;
    if (DENSEB) denBP[split*NN + row0 + l15] = dbL;
  }
}

// ---------------- merged sparse replay + fp64 refine (targets COMBINED arrays) ----------------
// Runs AFTER k_reduce. Class-dependent formulas (mirror the dense paths exactly):
//   neg (dense, both layers): ev_neg = hi-only
//   pos (sparse, both layers): ev_pos = hi+lo
//   bnd L1 (dotmode=1, sparse): bv = ehf*vh + (elf*vh + ehf*vl)  (3-term)
//   bnd L2 (dotmode=0, dense):  bv = ehf*vh                      (1-term)
__global__ void k_fix(const float* __restrict__ E, const double* __restrict__ nrm64,
    const ush* __restrict__ EhiT, const ush* __restrict__ EloT,
    const ush* __restrict__ VhT,  const ush* __restrict__ VloT,
    const ush* __restrict__ Qh,   const ush* __restrict__ Kh, int dotmode,
    const int* __restrict__ flag2Cnt, const float4* __restrict__ flags2,
    const int* __restrict__ flagCnt,  const float4* __restrict__ flags,
    float* __restrict__ Psum, float* __restrict__ Nsum, float* __restrict__ Bsum,
    float* __restrict__ cntP, float* __restrict__ cntN, float* __restrict__ denB)
{
  int lane = threadIdx.x & 63;
  if (blockIdx.x < 256){
    // ---- sparse pos/bnd replay ----
    int cnt = *flag2Cnt; if (cnt > FLAG2CAP) cnt = FLAG2CAP;
    int gw = (blockIdx.x * blockDim.x + threadIdx.x) >> 6;
    int nw = (256 * blockDim.x) >> 6;
    for (int idx = gw; idx < cnt; idx += nw){
      float4 rec = flags2[idx];
      int i = __float_as_int(rec.x);
      int jraw = __float_as_int(rec.y);
      int j = jraw & 0xFFFF, cls = jraw >> 16;
      if (cls == 0){
        #pragma unroll
        for (int h = 0; h < 2; h++){
          int d = lane + h*64;
          float ev = bf2f(EhiT[(size_t)d*NN + j]) + bf2f(EloT[(size_t)d*NN + j]);
          atomicAdd(&Psum[i*DD + d], ev);
        }
        if (lane == 0) atomicAdd(&cntP[i], 1.f);
      } else {
        float s = dotmode ? qkdot(Qh, Kh, i, j, lane) : rec.w;
        float e = __expf(s);
        float ehf = bf2f(f2bf(e));
        float elf = bf2f(f2bf(e - ehf));
        #pragma unroll
        for (int h = 0; h < 2; h++){
          int d = lane + h*64;
          float vh = bf2f(VhT [(size_t)d*NN + j]);
          float bv = ehf*vh;
          if (dotmode) bv += elf*vh + ehf*bf2f(VloT[(size_t)d*NN + j]);
          atomicAdd(&Bsum[i*DD + d], bv);
        }
        if (lane == 0) atomicAdd(&denB[i], e);
      }
    }
  } else {
    // ---- fp64 boundary refinement ----
    int cnt = *flagCnt; if (cnt > FLAGCAP) cnt = FLAGCAP;
    int gw = ((blockIdx.x - 256) * blockDim.x + threadIdx.x) >> 6;
    int nw = (512 * blockDim.x) >> 6;
    for (int idx = gw; idx < cnt; idx += nw){
      float4 rec = flags[idx];
      int i = __float_as_int(rec.x), j = __float_as_int(rec.y);
      float c = rec.z;
      float ei0 = E[i*DD + lane], ei1 = E[i*DD + 64 + lane];
      float ej0 = E[j*DD + lane], ej1 = E[j*DD + 64 + lane];
      double d = (double)ei0*(double)ej0 + (double)ei1*(double)ej1;
      #pragma unroll
      for (int m = 32; m; m >>= 1) d += __shfl_xor(d, m, 64);
      double se = d / (nrm64[i]*nrm64[j]);
      int ce = (se >= (double)ALPHA) ? 0 : ((se <= (double)BETA) ? 1 : 2);
      int cc = (c >= ALPHA) ? 0 : ((c <= BETA) ? 1 : 2);
      if (ce == cc) continue;
      float s = dotmode ? qkdot(Qh, Kh, i, j, lane) : rec.w;
      float e = __expf(s);
      float ehf = bf2f(f2bf(e));
      float elf = bf2f(f2bf(e - ehf));
      #pragma unroll
      for (int h = 0; h < 2; h++){
        int dd2 = lane + h*64;
        float evh = bf2f(EhiT[(size_t)dd2*NN + j]);
        float evp = evh + bf2f(EloT[(size_t)dd2*NN + j]);  // pos: hi+lo
        float vh = bf2f(VhT[(size_t)dd2*NN + j]);
        float bv = ehf*vh;
        if (dotmode) bv += elf*vh + ehf*bf2f(VloT[(size_t)dd2*NN + j]);
        float subv = (cc==0) ? -evp : (cc==1) ? -evh : -bv;
        float* subA = (cc==0) ? Psum : (cc==1) ? Nsum : Bsum;
        atomicAdd(&subA[i*DD + dd2], subv);
        float addv = (ce==0) ? evp : (ce==1) ? evh : bv;
        float* addA = (ce==0) ? Psum : (ce==1) ? Nsum : Bsum;
        atomicAdd(&addA[i*DD + dd2], addv);
      }
      if (lane == 0){
        float* subC = (cc==0) ? cntP : (cc==1) ? cntN : denB;
        atomicAdd(&subC[i], (cc==2) ? -e : -1.f);
        float* addC = (ce==0) ? cntP : (ce==1) ? cntN : denB;
        atomicAdd(&addC[i], (ce==2) ?  e :  1.f);
      }
    }
  }
}

extern "C" void kernel_launch(void* const* d_in, const int* in_sizes, int n_in,
                              void* d_out, int out_size, void* d_ws, size_t ws_size,
                              hipStream_t stream){
  const float* adj   = (const float*)d_in[0];
  const float* embed = (const float*)d_in[1];
  const float* gc_w  = (const float*)d_in[2];
  const float* gc_b  = (const float*)d_in[3];
  const float* wq = (const float*)d_in[4];
  const float* bq = (const float*)d_in[5];
  const float* wk = (const float*)d_in[6];
  const float* bk = (const float*)d_in[7];
  const float* wv = (const float*)d_in[8];
  const float* bv = (const float*)d_in[9];
  const float* g1w = (const float*)d_in[10];
  const float* g1b = (const float*)d_in[11];
  const float* g2w = (const float*)d_in[12];
  const float* g2b = (const float*)d_in[13];
  const float* lw  = (const float*)d_in[14];
  float* out = (float*)d_out;

  char* p = (char*)d_ws;
  auto alloc = [&](size_t bytes)->void*{ void* r = (void*)p; p += (bytes + 255) & ~(size_t)255; return r; };
  ush* qkvTh = (ush*)alloc(384*128*2);  ush* qkvTl = (ush*)alloc(384*128*2);
  ush* g1wTh = (ush*)alloc(512*256*2);  ush* g1wTl = (ush*)alloc(512*256*2);
  ush* gcwTh = (ush*)alloc(2*128*128*2); ush* gcwTl = (ush*)alloc(2*128*128*2);
  unsigned* adjw = (unsigned*)alloc((size_t)NN*256*4);
  double* nrm64 = (double*)alloc(NN*8);
  ush* Enh  = (ush*)alloc((size_t)NN*DD*2);
  ush* Enl  = (ush*)alloc((size_t)NN*DD*2);
  ush* EhiT = (ush*)alloc((size_t)NN*DD*2);
  ush* EloT = (ush*)alloc((size_t)NN*DD*2);
  ush* Qh   = (ush*)alloc((size_t)NN*DD*2);
  ush* Khb  = (ush*)alloc((size_t)NN*DD*2);
  ush* VhT  = (ush*)alloc((size_t)NN*DD*2);
  ush* VloT = (ush*)alloc((size_t)NN*DD*2);
  // per-split partial buffers (plain-store targets; NO zeroing needed)
  float* NsumP = (float*)alloc((size_t)8*NN*DD*4);
  float* BsumP = (float*)alloc((size_t)8*NN*DD*4);
  float* cntNP = (float*)alloc((size_t)8*NN*4);
  float* denBP = (float*)alloc((size_t)8*NN*4);
  // combined arrays; Nsum/cntN written by k_reduce (no zero); Psum/Bsum/cntP/denB
  // need zeroing (sparse-path targets in L1)
  float* Nsum = (float*)alloc((size_t)NN*DD*4);
  float* cntN = (float*)alloc(NN*4);
  char* zbase = p;
  float* Psum = (float*)alloc((size_t)NN*DD*4);
  float* Bsum = (float*)alloc((size_t)NN*DD*4);
  float* cntP = (float*)alloc(NN*4);
  float* denB = (float*)alloc(NN*4);
  int*   flagCnt  = (int*)alloc(256);
  int*   flag2Cnt = (int*)alloc(256);
  size_t zbytes = (size_t)(p - zbase);
  float4* flags  = (float4*)alloc((size_t)FLAGCAP*16);
  float4* flags2 = (float4*)alloc((size_t)FLAG2CAP*16);
  float* cur0 = (float*)alloc((size_t)NN*DD*4);

  // one-time prep (per call; inputs restored each replay)
  k_init<<<NN + 832, 256, 0, stream>>>(adj, adjw, wq, wk, wv, g1w, gc_w,
      qkvTh, qkvTl, g1wTh, g1wTl, gcwTh, gcwTl);

  const float* Ecur = embed;
  for (int l = 0; l < 2; l++){
    k_prep<<<2560, 256, 0, stream>>>(Ecur, nrm64, Enh, Enl, EhiT, EloT,
        qkvTh, qkvTl, bq, bk, bv, Qh, Khb, VhT, VloT);
    hipMemsetAsync(zbase, 0, zbytes, stream);
    if (l == 0)
      k_fused<0><<<(NN/BM)*CSPLIT, 256, 0, stream>>>(adjw, Enh, Enl, Qh, Khb,
          EhiT, EloT, VhT, VloT, NsumP, BsumP, cntNP, denBP,
          flagCnt, flags, flag2Cnt, flags2);
    else
      k_fused<1><<<(NN/BM)*CSPLIT, 256, 0, stream>>>(adjw, Enh, Enl, Qh, Khb,
          EhiT, EloT, VhT, VloT, NsumP, BsumP, cntNP, denBP,
          flagCnt, flags, flag2Cnt, flags2);
    k_reduce<<<(NN*DD/4 + NN + 255)/256, 256, 0, stream>>>(
        (const float4*)NsumP, (const float4*)BsumP, cntNP, denBP,
        (float4*)Nsum, (float4*)Bsum, cntN, denB, l);
    k_fix<<<768, 256, 0, stream>>>(Ecur, nrm64, EhiT, EloT, VhT, VloT,
        Qh, Khb, (l == 0) ? 1 : 0, flag2Cnt, flags2, flagCnt, flags,
        Psum, Nsum, Bsum, cntP, cntN, denB);
    k_mlp<<<512, 256, 0, stream>>>(Ecur, Psum, Bsum, Nsum, cntP, cntN, denB,
        g1wTh, g1wTl, g1b, g2w, g2b,
        gcwTh + l*128*128, gcwTl + l*128*128, gc_b + l*128,
        cur0, lw, l, (l == 0) ? cur0 : out);
    Ecur = (l == 0) ? cur0 : out;
  }
}

// Round 10
// 1045.689 us; speedup vs baseline: 1.3610x; 1.3610x over previous
//
#include <hip/hip_runtime.h>
#include <stdint.h>

#define NN 8192
#define DD 128
#define ALPHA 0.7f
#define BETA 0.3f
#define LAM 0.1f
#define QSCALE 0.08838834764831845f  // 1/sqrt(128)
#define DELTA 3e-5f      // L2 band: 3-term sim error ~1.5e-5
#define DELTA_L1 9e-3f   // L1 band: >= hi-only sim hard bound 7.85e-3
#define FLAGCAP 262144
#define FLAG2CAP 1048576

typedef __attribute__((ext_vector_type(8))) short short8;
typedef __attribute__((ext_vector_type(4))) float f32x4;
typedef unsigned short ush;

__device__ __forceinline__ ush f2bf(float f){
  union { float f; unsigned u; } v; v.f = f;
  return (ush)((v.u + 0x7FFFu + ((v.u >> 16) & 1u)) >> 16);
}
__device__ __forceinline__ float bf2f(ush s){
  union { unsigned u; float f; } v; v.u = ((unsigned)s) << 16; return v.f;
}

// identical scalar QK dot used by BOTH k_fix branches (L1 mode) so that the
// sparse add and any later refine subtract use the exact same s.
__device__ __forceinline__ float qkdot(const ush* __restrict__ Qh,
                                       const ush* __restrict__ Kh,
                                       int i, int j, int lane){
  float q0 = bf2f(Qh[i*DD + lane]),      k0 = bf2f(Kh[j*DD + lane]);
  float q1 = bf2f(Qh[i*DD + 64 + lane]), k1 = bf2f(Kh[j*DD + 64 + lane]);
  float s = q0*k0 + q1*k1;
  #pragma unroll
  for (int m = 32; m; m >>= 1) s += __shfl_xor(s, m, 64);
  return s;
}

// ---------------- one-time init: adjacency pack | weight transposes ----------------
__global__ void k_init(const float* __restrict__ adj, unsigned* __restrict__ adjw,
                       const float* __restrict__ wq, const float* __restrict__ wk,
                       const float* __restrict__ wv, const float* __restrict__ g1w,
                       const float* __restrict__ gcw,
                       ush* __restrict__ qkvTh, ush* __restrict__ qkvTl,
                       ush* __restrict__ g1wTh, ush* __restrict__ g1wTl,
                       ush* __restrict__ gcwTh, ush* __restrict__ gcwTl){
  if (blockIdx.x < NN){
    int i = blockIdx.x, wave = threadIdx.x >> 6, lane = threadIdx.x & 63;
    for (int seg = wave; seg < 128; seg += 4){
      int j = seg*64 + lane;
      unsigned long long bm = __ballot(adj[(size_t)i*NN + j] != 0.0f);
      if (lane == 0)  adjw[i*256 + seg*2]     = (unsigned)bm;
      if (lane == 32) adjw[i*256 + seg*2 + 1] = (unsigned)(bm >> 32);
    }
    return;
  }
  int idx = (blockIdx.x - NN)*256 + threadIdx.x;
  const float* src; ush *dh, *dl; int K, Nout, li;
  if      (idx <  16384){ src=wq;        dh=qkvTh;        dl=qkvTl;        K=128; Nout=128; li=idx; }
  else if (idx <  32768){ src=wk;        dh=qkvTh+16384;  dl=qkvTl+16384;  K=128; Nout=128; li=idx-16384; }
  else if (idx <  49152){ src=wv;        dh=qkvTh+32768;  dl=qkvTl+32768;  K=128; Nout=128; li=idx-32768; }
  else if (idx < 180224){ src=g1w;       dh=g1wTh;        dl=g1wTl;        K=512; Nout=256; li=idx-49152; }
  else if (idx < 196608){ src=gcw;       dh=gcwTh;        dl=gcwTl;        K=128; Nout=128; li=idx-180224; }
  else if (idx < 212992){ src=gcw+16384; dh=gcwTh+16384;  dl=gcwTl+16384;  K=128; Nout=128; li=idx-196608; }
  else return;
  int k = li / Nout, n = li - k*Nout;
  float v = src[li];
  ush h = f2bf(v);
  dh[n*K + k] = h;
  dl[n*K + k] = f2bf(v - bf2f(h));
}

// ---------------- merged per-layer prep: norm | transsplit | qkv (block-range) ----------------
__global__ void k_prep(const float* __restrict__ E, double* __restrict__ nrm64,
                       ush* __restrict__ Enh, ush* __restrict__ Enl,
                       ush* __restrict__ EhiT, ush* __restrict__ EloT,
                       const ush* __restrict__ BtH, const ush* __restrict__ BtL,
                       const float* __restrict__ bq, const float* __restrict__ bk,
                       const float* __restrict__ bv,
                       ush* __restrict__ Qh, ush* __restrict__ Kh,
                       ush* __restrict__ VhT, ush* __restrict__ VloT){
  __shared__ float t[64][65];
  __shared__ float sV[128*33];
  int bid = blockIdx.x, tid = threadIdx.x;
  if (bid < 2048){
    // ---- norm: 4 rows/block ----
    int i = bid*4 + (tid >> 6);
    int l = tid & 63;
    float v0 = E[i*DD + l], v1 = E[i*DD + 64 + l];
    double ss = (double)v0*(double)v0 + (double)v1*(double)v1;
    #pragma unroll
    for (int m = 32; m; m >>= 1) ss += __shfl_xor(ss, m, 64);
    double nr = sqrt(ss); if (nr < 1e-8) nr = 1e-8;
    float inv = (float)(1.0 / nr);
    float n0 = v0*inv, n1 = v1*inv;
    ush h0 = f2bf(n0), h1 = f2bf(n1);
    Enh[i*DD + l] = h0;       Enh[i*DD + 64 + l] = h1;
    Enl[i*DD + l] = f2bf(n0 - bf2f(h0));
    Enl[i*DD + 64 + l] = f2bf(n1 - bf2f(h1));
    if (l == 0) nrm64[i] = nr;
  } else if (bid < 2304){
    // ---- transsplit: fp32 [8192,128] -> hi/lo bf16 T [128,8192] ----
    int lin = bid - 2048;
    int r0 = (lin >> 1) * 64, c0 = (lin & 1) * 64;
    for (int idx = tid; idx < 4096; idx += 256){
      int r = idx >> 6, c = idx & 63;
      t[r][c] = E[(r0 + r)*DD + c0 + c];
    }
    __syncthreads();
    for (int idx = tid; idx < 4096; idx += 256){
      int c = idx >> 6, r = idx & 63;
      float v = t[r][c];
      ush h = f2bf(v);
      EhiT[(size_t)(c0 + c)*NN + r0 + r] = h;
      EloT[(size_t)(c0 + c)*NN + r0 + r] = f2bf(v - bf2f(h));
    }
  } else {
    // ---- qkv: fused Q/K/V projection; V written transposed+split via LDS ----
    int lane = tid & 63, wave = tid >> 6;
    int l15 = lane & 15, quad = lane >> 4;
    int rowblk = (bid - 2304) * 32;
    int row16 = rowblk + (wave >> 1)*16;
    int nf0 = (wave & 1)*12;
    f32x4 acc[12];
    #pragma unroll
    for (int i = 0; i < 12; i++){ f32x4 z = {0.f,0.f,0.f,0.f}; acc[i] = z; }
    #pragma unroll
    for (int kk = 0; kk < 4; kk++){
      const float* ap = &E[(row16 + l15)*DD + kk*32 + quad*8];
      short8 ah, al;
      #pragma unroll
      for (int j = 0; j < 8; j++){
        float v = ap[j];
        ush h = f2bf(v);
        ah[j] = (short)h; al[j] = (short)f2bf(v - bf2f(h));
      }
      #pragma unroll
      for (int i = 0; i < 12; i++){
        int bo = ((nf0 + i)*16 + l15)*DD + kk*32 + quad*8;
        short8 bh = *(const short8*)&BtH[bo];
        short8 bl = *(const short8*)&BtL[bo];
        acc[i] = __builtin_amdgcn_mfma_f32_16x16x32_bf16(ah, bh, acc[i], 0, 0, 0);
        acc[i] = __builtin_amdgcn_mfma_f32_16x16x32_bf16(al, bh, acc[i], 0, 0, 0);
        acc[i] = __builtin_amdgcn_mfma_f32_16x16x32_bf16(ah, bl, acc[i], 0, 0, 0);
      }
    }
    #pragma unroll
    for (int i = 0; i < 12; i++){
      int nfg = nf0 + i;
      int grp = nfg >> 3;
      int col = (nfg & 7)*16 + l15;
      float b = (grp == 0) ? bq[col] : (grp == 1) ? bk[col] : bv[col];
      #pragma unroll
      for (int r = 0; r < 4; r++){
        int row = row16 + quad*4 + r;
        float v = acc[i][r] + b;
        if (grp == 0)      Qh[row*DD + col] = f2bf(v * QSCALE);
        else if (grp == 1) Kh[row*DD + col] = f2bf(v);
        else               sV[col*33 + (row - rowblk)] = v;
      }
    }
    __syncthreads();
    int feat = tid >> 1, rh = (tid & 1)*16;
    ush hh[16], ll[16];
    #pragma unroll
    for (int j = 0; j < 16; j++){
      float v = sV[feat*33 + rh + j];
      ush h = f2bf(v);
      hh[j] = h; ll[j] = f2bf(v - bf2f(h));
    }
    size_t go = (size_t)feat*NN + rowblk + rh;
    *(uint4*)&VhT [go]     = *(const uint4*)&hh[0];
    *(uint4*)&VhT [go + 8] = *(const uint4*)&hh[8];
    *(uint4*)&VloT[go]     = *(const uint4*)&ll[0];
    *(uint4*)&VloT[go + 8] = *(const uint4*)&ll[8];
  }
}

// ---------------- fused MLP: g1 GEMM -> (LDS h) -> gate/fusion/gc GEMM ----------------
__global__ void k_mlp(const float* __restrict__ E, const float* __restrict__ P,
                      const float* __restrict__ B, const float* __restrict__ N,
                      const float* __restrict__ cntP, const float* __restrict__ cntN,
                      const float* __restrict__ denB,
                      const ush* __restrict__ g1Th, const ush* __restrict__ g1Tl,
                      const float* __restrict__ g1b,
                      const float* __restrict__ g2w, const float* __restrict__ g2b,
                      const ush* __restrict__ gcTh, const ush* __restrict__ gcTl,
                      const float* __restrict__ gcb,
                      const float* __restrict__ prevC, const float* __restrict__ lwv,
                      int dofinal, float* __restrict__ out){
  __shared__ float sH[16*260];
  int tid = threadIdx.x, lane = tid & 63, wave = tid >> 6;
  int l15 = lane & 15, quad = lane >> 4;
  int row16 = blockIdx.x*16;
  int row = row16 + l15;
  float cp = cntP[row], cn = cntN[row], dn = denB[row];
  // ---- phase 1: g1 (4-nf waves over 256 cols) ----
  {
    int nf0 = wave*4;
    float rs[4] = {1.f, 1.f/fmaxf(cp,1.f), (dn > 0.5f) ? (1.f/dn) : 0.f, LAM/fmaxf(cn,1.f)};
    const float* bases[4] = {E, P, B, N};
    f32x4 acc[4];
    #pragma unroll
    for (int nf = 0; nf < 4; nf++){ f32x4 z = {0.f,0.f,0.f,0.f}; acc[nf] = z; }
    #pragma unroll
    for (int kk = 0; kk < 16; kk++){
      const float* ap = &bases[kk>>2][row*DD + (kk&3)*32 + quad*8];
      float sc = rs[kk>>2];
      short8 ah, al;
      #pragma unroll
      for (int j = 0; j < 8; j++){
        float v = ap[j] * sc;
        ush h = f2bf(v);
        ah[j] = (short)h; al[j] = (short)f2bf(v - bf2f(h));
      }
      #pragma unroll
      for (int nf = 0; nf < 4; nf++){
        int bo = ((nf0 + nf)*16 + l15)*512 + kk*32 + quad*8;
        short8 bh = *(const short8*)&g1Th[bo];
        short8 bl = *(const short8*)&g1Tl[bo];
        acc[nf] = __builtin_amdgcn_mfma_f32_16x16x32_bf16(ah, bh, acc[nf], 0, 0, 0);
        acc[nf] = __builtin_amdgcn_mfma_f32_16x16x32_bf16(al, bh, acc[nf], 0, 0, 0);
        acc[nf] = __builtin_amdgcn_mfma_f32_16x16x32_bf16(ah, bl, acc[nf], 0, 0, 0);
      }
    }
    #pragma unroll
    for (int nf = 0; nf < 4; nf++){
      int col = (nf0 + nf)*16 + l15;
      float b = g1b[col];
      #pragma unroll
      for (int r = 0; r < 4; r++)
        sH[(quad*4 + r)*260 + col] = fmaxf(acc[nf][r] + b, 0.f);
    }
  }
  __syncthreads();
  // ---- phase 2: gate + fusion + gc GEMM (2-nf waves over 128 cols) ----
  {
    int nf0 = wave*2;
    float l0=0,l1=0,l2=0,l3=0;
    #pragma unroll
    for (int i = 0; i < 16; i++){
      float4 hv = *(const float4*)&sH[l15*260 + quad*64 + i*4];
      float hvv[4] = {hv.x, hv.y, hv.z, hv.w};
      #pragma unroll
      for (int j = 0; j < 4; j++){
        float4 w4 = *(const float4*)&g2w[(quad*64 + i*4 + j)*4];
        l0 = fmaf(hvv[j], w4.x, l0); l1 = fmaf(hvv[j], w4.y, l1);
        l2 = fmaf(hvv[j], w4.z, l2); l3 = fmaf(hvv[j], w4.w, l3);
      }
    }
    l0 += __shfl_xor(l0,16,64); l0 += __shfl_xor(l0,32,64);
    l1 += __shfl_xor(l1,16,64); l1 += __shfl_xor(l1,32,64);
    l2 += __shfl_xor(l2,16,64); l2 += __shfl_xor(l2,32,64);
    l3 += __shfl_xor(l3,16,64); l3 += __shfl_xor(l3,32,64);
    l0 += g2b[0]; l1 += g2b[1]; l2 += g2b[2]; l3 += g2b[3];
    float mx = fmaxf(fmaxf(l0,l1), fmaxf(l2,l3));
    float e0 = __expf(l0-mx), e1 = __expf(l1-mx), e2 = __expf(l2-mx), e3 = __expf(l3-mx);
    float inv = 1.f/(e0+e1+e2+e3);
    float g0 = e0*inv, g1v = e1*inv, g2v = e2*inv, g3 = e3*inv;
    bool any = (cp + cn > 0.5f) || (dn > 0.5f);
    float pscl = g1v/fmaxf(cp,1.f);
    float bscl = (dn > 0.5f) ? (g2v/dn) : 0.f;
    float nscl = LAM*g3/fmaxf(cn,1.f);
    f32x4 acc[2];
    #pragma unroll
    for (int nf = 0; nf < 2; nf++){ f32x4 z = {0.f,0.f,0.f,0.f}; acc[nf] = z; }
    #pragma unroll
    for (int kk = 0; kk < 4; kk++){
      int koff = row*DD + kk*32 + quad*8;
      short8 ah, al;
      #pragma unroll
      for (int j = 0; j < 8; j++){
        float ev = E[koff + j];
        float v = any ? (g0*ev + pscl*P[koff+j] + bscl*B[koff+j] + nscl*N[koff+j]) : ev;
        ush h = f2bf(v);
        ah[j] = (short)h; al[j] = (short)f2bf(v - bf2f(h));
      }
      #pragma unroll
      for (int nf = 0; nf < 2; nf++){
        int bo = ((nf0 + nf)*16 + l15)*DD + kk*32 + quad*8;
        short8 bh = *(const short8*)&gcTh[bo];
        short8 bl = *(const short8*)&gcTl[bo];
        acc[nf] = __builtin_amdgcn_mfma_f32_16x16x32_bf16(ah, bh, acc[nf], 0, 0, 0);
        acc[nf] = __builtin_amdgcn_mfma_f32_16x16x32_bf16(al, bh, acc[nf], 0, 0, 0);
        acc[nf] = __builtin_amdgcn_mfma_f32_16x16x32_bf16(ah, bl, acc[nf], 0, 0, 0);
      }
    }
    float we0 = 0.5f, we1 = 0.5f;
    if (dofinal){
      float a0 = lwv[0], a1 = lwv[1];
      float mw = fmaxf(a0, a1);
      float x0 = __expf(a0-mw), x1 = __expf(a1-mw);
      float iv = 1.f/(x0+x1);
      we0 = x0*iv; we1 = x1*iv;
    }
    #pragma unroll
    for (int nf = 0; nf < 2; nf++){
      int col = (nf0 + nf)*16 + l15;
      float b = gcb[col];
      #pragma unroll
      for (int r = 0; r < 4; r++){
        int rr = row16 + quad*4 + r;
        float val = fmaxf(acc[nf][r] + b, 0.f);
        if (dofinal) val = we0*prevC[rr*DD + col] + we1*val;
        out[rr*DD + col] = val;
      }
    }
  }
}

// ---------------- fused sim/classify/aggregate (R7 schedule FROZEN; R15 config) ----------------
// R17 = exact revert to R15 (measured 1043.5 us). R16's CSPLIT=8 + private-partial
// experiment refuted the atomics-only theory: read-side L2 locality collapses at
// grid>512 regardless of write mechanism (FETCH 25MB -> 665MB). The proven
// envelope is CSPLIT=4 / 256-thr / grid 512 = one co-resident generation.
#define BM 64
#define BN 32
#define CSPLIT 4
#define CCHUNK (NN/CSPLIT)
#define NTILES (CCHUNK/BN)
#define RSTRIDE 136
#define FSTRIDE 80
#define MSTRIDE 80

template<int DENSEB>
__launch_bounds__(256, 2)
__global__ void k_fused(const unsigned* __restrict__ adjw,
    const ush* __restrict__ Enh, const ush* __restrict__ Enl,
    const ush* __restrict__ Qh,  const ush* __restrict__ Kh,
    const ush* __restrict__ EhiT, const ush* __restrict__ EloT,
    const ush* __restrict__ VhT,  const ush* __restrict__ VloT,
    float* __restrict__ Nsum, float* __restrict__ Bsum,
    float* __restrict__ cntN, float* __restrict__ denB,
    int* __restrict__ flagCnt, float4* __restrict__ flags,
    int* __restrict__ flag2Cnt, float4* __restrict__ flags2)
{
  __shared__ __attribute__((aligned(16))) ush sEnh[32*RSTRIDE];
  __shared__ __attribute__((aligned(16))) ush sEnl[DENSEB ? 32*RSTRIDE : 16];
  __shared__ __attribute__((aligned(16))) ush sKh [DENSEB ? 32*RSTRIDE : 16];
  __shared__ __attribute__((aligned(16))) ush sE2 [128*FSTRIDE];
  __shared__ __attribute__((aligned(16))) ush sV2 [DENSEB ? 128*FSTRIDE : 16];
  __shared__ __attribute__((aligned(16))) ush sM  [4][16*MSTRIDE];

  const float del = DENSEB ? DELTA : DELTA_L1;
  int tid = threadIdx.x, lane = tid & 63, wave = tid >> 6;
  int l15 = lane & 15, quad = lane >> 4;
  int rowblk = blockIdx.x >> 2, split = blockIdx.x & 3;
  int row0 = rowblk * BM + wave * 16;
  int col0 = split * CCHUNK;

  short8 bEnh[4], bEnl[4], bQ[4];
  #pragma unroll
  for (int kf = 0; kf < 4; kf++){
    int go = (row0 + l15)*DD + kf*32 + quad*8;
    bEnh[kf] = *(const short8*)&Enh[go];
    if (DENSEB){
      bEnl[kf] = *(const short8*)&Enl[go];
      bQ[kf] = *(const short8*)&Qh[go];
    }
  }

  f32x4 accN[8], accB[DENSEB ? 8 : 1];
  #pragma unroll
  for (int nf = 0; nf < 8; nf++){ f32x4 z = {0.f,0.f,0.f,0.f}; accN[nf]=z; }
  if (DENSEB){
    #pragma unroll
    for (int nf = 0; nf < 8; nf++){ f32x4 z = {0.f,0.f,0.f,0.f}; accB[nf]=z; }
  }
  float cnL = 0.f, dbL = 0.f;

  int f0 = tid >> 2,        n0 = (tid & 3)*8;
  int f1 = (tid+256) >> 2,  n1 = ((tid+256) & 3)*8;
  uint4 pEh0, pEh1, pVh0, pVh1;
  {
    size_t g0 = (size_t)f0*NN + col0 + n0, g1 = (size_t)f1*NN + col0 + n1;
    pEh0 = *(const uint4*)&EhiT[g0]; pEh1 = *(const uint4*)&EhiT[g1];
    if (DENSEB){
      pVh0 = *(const uint4*)&VhT [g0]; pVh1 = *(const uint4*)&VhT [g1];
    }
  }
  int rr0 = tid >> 4,       ro0 = (tid & 15)*8;
  int rr1 = (tid+256) >> 4, ro1 = ((tid+256) & 15)*8;

  for (int t = 0; t < NTILES; t++){
    int c0 = col0 + t*BN;
    __syncthreads();
    *(uint4*)&sE2[f0*FSTRIDE + n0] = pEh0;  *(uint4*)&sE2[f1*FSTRIDE + n1] = pEh1;
    if (DENSEB){
      *(uint4*)&sV2[f0*FSTRIDE + n0] = pVh0;  *(uint4*)&sV2[f1*FSTRIDE + n1] = pVh1;
    }
    {
      uint4 a0 = *(const uint4*)&Enh[(c0 + rr0)*DD + ro0];
      uint4 a1 = *(const uint4*)&Enh[(c0 + rr1)*DD + ro1];
      *(uint4*)&sEnh[rr0*RSTRIDE + ro0] = a0;  *(uint4*)&sEnh[rr1*RSTRIDE + ro1] = a1;
      if (DENSEB){
        uint4 b0 = *(const uint4*)&Enl[(c0 + rr0)*DD + ro0];
        uint4 b1 = *(const uint4*)&Enl[(c0 + rr1)*DD + ro1];
        uint4 k0 = *(const uint4*)&Kh [(c0 + rr0)*DD + ro0];
        uint4 k1 = *(const uint4*)&Kh [(c0 + rr1)*DD + ro1];
        *(uint4*)&sEnl[rr0*RSTRIDE + ro0] = b0;  *(uint4*)&sEnl[rr1*RSTRIDE + ro1] = b1;
        *(uint4*)&sKh [rr0*RSTRIDE + ro0] = k0;  *(uint4*)&sKh [rr1*RSTRIDE + ro1] = k1;
      }
    }
    __syncthreads();
    if (t + 1 < NTILES){
      int c1 = c0 + BN;
      size_t g0 = (size_t)f0*NN + c1 + n0, g1 = (size_t)f1*NN + c1 + n1;
      pEh0 = *(const uint4*)&EhiT[g0]; pEh1 = *(const uint4*)&EhiT[g1];
      if (DENSEB){
        pVh0 = *(const uint4*)&VhT [g0]; pVh1 = *(const uint4*)&VhT [g1];
      }
    }
    unsigned aw = adjw[(row0 + l15)*256 + (c0 >> 5)];

    f32x4 simT[2], svT[2];
    { f32x4 z = {0.f,0.f,0.f,0.f}; simT[0]=z; simT[1]=z; svT[0]=z; svT[1]=z; }
    #pragma unroll
    for (int f = 0; f < 2; f++){
      #pragma unroll
      for (int kf = 0; kf < 4; kf++){
        int la = (f*16 + l15)*RSTRIDE + kf*32 + quad*8;
        short8 ch = *(const short8*)&sEnh[la];
        simT[f] = __builtin_amdgcn_mfma_f32_16x16x32_bf16(ch, bEnh[kf], simT[f],0,0,0);
        if (DENSEB){
          short8 cl = *(const short8*)&sEnl[la];
          short8 ck = *(const short8*)&sKh [la];
          simT[f] = __builtin_amdgcn_mfma_f32_16x16x32_bf16(cl, bEnh[kf], simT[f],0,0,0);
          simT[f] = __builtin_amdgcn_mfma_f32_16x16x32_bf16(ch, bEnl[kf], simT[f],0,0,0);
          svT [f] = __builtin_amdgcn_mfma_f32_16x16x32_bf16(ck, bQ  [kf], svT [f],0,0,0);
        }
      }
    }
    ushort4 ehv[2];
    unsigned flagb = 0, spb = 0;
    #pragma unroll
    for (int f = 0; f < 2; f++){
      ush vn2[4], veh[4];
      #pragma unroll
      for (int r = 0; r < 4; r++){
        int cbit = f*16 + quad*4 + r;
        bool nbr = (aw >> cbit) & 1u;
        float c = simT[f][r];
        bool pos = nbr && (c >= ALPHA);
        bool neg = nbr && (c <= BETA);
        bool bnd = nbr && !pos && !neg;
        vn2[r] = neg ? (ush)0x3F80 : (ush)0;
        cnL += neg ? 1.f : 0.f;
        if (DENSEB){
          float e = bnd ? __expf(svT[f][r]) : 0.f;
          veh[r] = f2bf(e);
          dbL += e;
        }
        if (nbr && (fabsf(c - ALPHA) < del || fabsf(c - BETA) < del))
          flagb |= 1u << (f*4 + r);
        if (pos || (!DENSEB && bnd))
          spb |= 1u << (f*4 + r);
      }
      int mb = l15*MSTRIDE + f*16 + quad*4;
      *(ushort4*)&sM[wave][mb] = make_ushort4(vn2[0],vn2[1],vn2[2],vn2[3]);
      if (DENSEB)
        ehv[f] = make_ushort4(veh[0],veh[1],veh[2],veh[3]);
    }
    if (__ballot((flagb | spb) != 0)){
      #pragma unroll
      for (int f = 0; f < 2; f++){
        #pragma unroll
        for (int r = 0; r < 4; r++){
          int bit = f*4 + r;
          bool fl = (flagb >> bit) & 1u;
          unsigned long long bm = __ballot(fl);
          if (bm){
            int leader = __ffsll((long long)bm) - 1;
            int base = 0;
            if (lane == leader) base = atomicAdd(flagCnt, __popcll(bm));
            base = __shfl(base, leader, 64);
            if (fl){
              int id = base + __popcll(bm & ((1ull << lane) - 1ull));
              if (id < FLAGCAP){
                float4 rec;
                rec.x = __int_as_float(row0 + l15);
                rec.y = __int_as_float(c0 + f*16 + quad*4 + r);
                rec.z = simT[f][r];
                rec.w = DENSEB ? svT[f][r] : 0.f;
                flags[id] = rec;
              }
            }
          }
          bool f2 = (spb >> bit) & 1u;
          unsigned long long bm2 = __ballot(f2);
          if (bm2){
            int leader = __ffsll((long long)bm2) - 1;
            int base = 0;
            if (lane == leader) base = atomicAdd(flag2Cnt, __popcll(bm2));
            base = __shfl(base, leader, 64);
            if (f2){
              int id = base + __popcll(bm2 & ((1ull << lane) - 1ull));
              if (id < FLAG2CAP){
                float c = simT[f][r];
                int j = c0 + f*16 + quad*4 + r;
                int cls = (c >= ALPHA) ? 0 : 1;
                float4 rec;
                rec.x = __int_as_float(row0 + l15);
                rec.y = __int_as_float(j | (cls << 16));
                rec.z = c;
                rec.w = DENSEB ? svT[f][r] : 0.f;
                flags2[id] = rec;
              }
            }
          }
        }
      }
    }
    {
      short8 mNeg = *(const short8*)&sM[wave][l15*MSTRIDE + quad*8];
      #pragma unroll
      for (int nf = 0; nf < 8; nf++){
        int so = (nf*16 + l15)*FSTRIDE + quad*8;
        short8 eth = *(const short8*)&sE2[so];
        accN[nf] = __builtin_amdgcn_mfma_f32_16x16x32_bf16(mNeg, eth, accN[nf],0,0,0);
      }
    }
    if (DENSEB){
      int mb0 = l15*MSTRIDE + quad*4;
      *(ushort4*)&sM[wave][mb0]      = ehv[0];
      *(ushort4*)&sM[wave][mb0 + 16] = ehv[1];
      short8 mEh = *(const short8*)&sM[wave][l15*MSTRIDE + quad*8];
      #pragma unroll
      for (int nf = 0; nf < 8; nf++){
        int so = (nf*16 + l15)*FSTRIDE + quad*8;
        short8 vth = *(const short8*)&sV2[so];
        accB[nf] = __builtin_amdgcn_mfma_f32_16x16x32_bf16(mEh, vth, accB[nf],0,0,0);
      }
    }
  }
  #pragma unroll
  for (int nf = 0; nf < 8; nf++){
    int col = nf*16 + l15;
    #pragma unroll
    for (int r = 0; r < 4; r++){
      int row = row0 + quad*4 + r;
      atomicAdd(&Nsum[row*DD + col], accN[nf][r]);
      if (DENSEB) atomicAdd(&Bsum[row*DD + col], accB[nf][r]);
    }
  }
  cnL += __shfl_xor(cnL, 16, 64); cnL += __shfl_xor(cnL, 32, 64);
  if (DENSEB){ dbL += __shfl_xor(dbL, 16, 64); dbL += __shfl_xor(dbL, 32, 64); }
  if (quad == 0){
    atomicAdd(&cntN[row0 + l15], cnL);
    if (DENSEB) atomicAdd(&denB[row0 + l15], dbL);
  }
}

// ---------------- merged sparse replay + fp64 refine (commuting atomics) ----------------
// Class-dependent formulas (mirror the dense paths exactly):
//   neg (dense, both layers): ev_neg = hi-only
//   pos (sparse, both layers): ev_pos = hi+lo
//   bnd L1 (dotmode=1, sparse): bv = ehf*vh + (elf*vh + ehf*vl)  (3-term)
//   bnd L2 (dotmode=0, dense):  bv = ehf*vh                      (1-term)
__global__ void k_fix(const float* __restrict__ E, const double* __restrict__ nrm64,
    const ush* __restrict__ EhiT, const ush* __restrict__ EloT,
    const ush* __restrict__ VhT,  const ush* __restrict__ VloT,
    const ush* __restrict__ Qh,   const ush* __restrict__ Kh, int dotmode,
    const int* __restrict__ flag2Cnt, const float4* __restrict__ flags2,
    const int* __restrict__ flagCnt,  const float4* __restrict__ flags,
    float* __restrict__ Psum, float* __restrict__ Nsum, float* __restrict__ Bsum,
    float* __restrict__ cntP, float* __restrict__ cntN, float* __restrict__ denB)
{
  int lane = threadIdx.x & 63;
  if (blockIdx.x < 256){
    // ---- sparse pos/bnd replay ----
    int cnt = *flag2Cnt; if (cnt > FLAG2CAP) cnt = FLAG2CAP;
    int gw = (blockIdx.x * blockDim.x + threadIdx.x) >> 6;
    int nw = (256 * blockDim.x) >> 6;
    for (int idx = gw; idx < cnt; idx += nw){
      float4 rec = flags2[idx];
      int i = __float_as_int(rec.x);
      int jraw = __float_as_int(rec.y);
      int j = jraw & 0xFFFF, cls = jraw >> 16;
      if (cls == 0){
        #pragma unroll
        for (int h = 0; h < 2; h++){
          int d = lane + h*64;
          float ev = bf2f(EhiT[(size_t)d*NN + j]) + bf2f(EloT[(size_t)d*NN + j]);
          atomicAdd(&Psum[i*DD + d], ev);
        }
        if (lane == 0) atomicAdd(&cntP[i], 1.f);
      } else {
        float s = dotmode ? qkdot(Qh, Kh, i, j, lane) : rec.w;
        float e = __expf(s);
        float ehf = bf2f(f2bf(e));
        float elf = bf2f(f2bf(e - ehf));
        #pragma unroll
        for (int h = 0; h < 2; h++){
          int d = lane + h*64;
          float vh = bf2f(VhT [(size_t)d*NN + j]);
          float bv = ehf*vh;
          if (dotmode) bv += elf*vh + ehf*bf2f(VloT[(size_t)d*NN + j]);
          atomicAdd(&Bsum[i*DD + d], bv);
        }
        if (lane == 0) atomicAdd(&denB[i], e);
      }
    }
  } else {
    // ---- fp64 boundary refinement ----
    int cnt = *flagCnt; if (cnt > FLAGCAP) cnt = FLAGCAP;
    int gw = ((blockIdx.x - 256) * blockDim.x + threadIdx.x) >> 6;
    int nw = (512 * blockDim.x) >> 6;
    for (int idx = gw; idx < cnt; idx += nw){
      float4 rec = flags[idx];
      int i = __float_as_int(rec.x), j = __float_as_int(rec.y);
      float c = rec.z;
      float ei0 = E[i*DD + lane], ei1 = E[i*DD + 64 + lane];
      float ej0 = E[j*DD + lane], ej1 = E[j*DD + 64 + lane];
      double d = (double)ei0*(double)ej0 + (double)ei1*(double)ej1;
      #pragma unroll
      for (int m = 32; m; m >>= 1) d += __shfl_xor(d, m, 64);
      double se = d / (nrm64[i]*nrm64[j]);
      int ce = (se >= (double)ALPHA) ? 0 : ((se <= (double)BETA) ? 1 : 2);
      int cc = (c >= ALPHA) ? 0 : ((c <= BETA) ? 1 : 2);
      if (ce == cc) continue;
      float s = dotmode ? qkdot(Qh, Kh, i, j, lane) : rec.w;
      float e = __expf(s);
      float ehf = bf2f(f2bf(e));
      float elf = bf2f(f2bf(e - ehf));
      #pragma unroll
      for (int h = 0; h < 2; h++){
        int dd2 = lane + h*64;
        float evh = bf2f(EhiT[(size_t)dd2*NN + j]);
        float evp = evh + bf2f(EloT[(size_t)dd2*NN + j]);  // pos: hi+lo
        float vh = bf2f(VhT[(size_t)dd2*NN + j]);
        float bv = ehf*vh;
        if (dotmode) bv += elf*vh + ehf*bf2f(VloT[(size_t)dd2*NN + j]);
        float subv = (cc==0) ? -evp : (cc==1) ? -evh : -bv;
        float* subA = (cc==0) ? Psum : (cc==1) ? Nsum : Bsum;
        atomicAdd(&subA[i*DD + dd2], subv);
        float addv = (ce==0) ? evp : (ce==1) ? evh : bv;
        float* addA = (ce==0) ? Psum : (ce==1) ? Nsum : Bsum;
        atomicAdd(&addA[i*DD + dd2], addv);
      }
      if (lane == 0){
        float* subC = (cc==0) ? cntP : (cc==1) ? cntN : denB;
        atomicAdd(&subC[i], (cc==2) ? -e : -1.f);
        float* addC = (ce==0) ? cntP : (ce==1) ? cntN : denB;
        atomicAdd(&addC[i], (ce==2) ?  e :  1.f);
      }
    }
  }
}

extern "C" void kernel_launch(void* const* d_in, const int* in_sizes, int n_in,
                              void* d_out, int out_size, void* d_ws, size_t ws_size,
                              hipStream_t stream){
  const float* adj   = (const float*)d_in[0];
  const float* embed = (const float*)d_in[1];
  const float* gc_w  = (const float*)d_in[2];
  const float* gc_b  = (const float*)d_in[3];
  const float* wq = (const float*)d_in[4];
  const float* bq = (const float*)d_in[5];
  const float* wk = (const float*)d_in[6];
  const float* bk = (const float*)d_in[7];
  const float* wv = (const float*)d_in[8];
  const float* bv = (const float*)d_in[9];
  const float* g1w = (const float*)d_in[10];
  const float* g1b = (const float*)d_in[11];
  const float* g2w = (const float*)d_in[12];
  const float* g2b = (const float*)d_in[13];
  const float* lw  = (const float*)d_in[14];
  float* out = (float*)d_out;

  char* p = (char*)d_ws;
  auto alloc = [&](size_t bytes)->void*{ void* r = (void*)p; p += (bytes + 255) & ~(size_t)255; return r; };
  ush* qkvTh = (ush*)alloc(384*128*2);  ush* qkvTl = (ush*)alloc(384*128*2);
  ush* g1wTh = (ush*)alloc(512*256*2);  ush* g1wTl = (ush*)alloc(512*256*2);
  ush* gcwTh = (ush*)alloc(2*128*128*2); ush* gcwTl = (ush*)alloc(2*128*128*2);
  unsigned* adjw = (unsigned*)alloc((size_t)NN*256*4);
  double* nrm64 = (double*)alloc(NN*8);
  ush* Enh  = (ush*)alloc((size_t)NN*DD*2);
  ush* Enl  = (ush*)alloc((size_t)NN*DD*2);
  ush* EhiT = (ush*)alloc((size_t)NN*DD*2);
  ush* EloT = (ush*)alloc((size_t)NN*DD*2);
  ush* Qh   = (ush*)alloc((size_t)NN*DD*2);
  ush* Khb  = (ush*)alloc((size_t)NN*DD*2);
  ush* VhT  = (ush*)alloc((size_t)NN*DD*2);
  ush* VloT = (ush*)alloc((size_t)NN*DD*2);
  char* zbase = p;
  float* Psum = (float*)alloc((size_t)NN*DD*4);
  float* Nsum = (float*)alloc((size_t)NN*DD*4);
  float* Bsum = (float*)alloc((size_t)NN*DD*4);
  float* cntP = (float*)alloc(NN*4);
  float* cntN = (float*)alloc(NN*4);
  float* denB = (float*)alloc(NN*4);
  int*   flagCnt  = (int*)alloc(256);
  int*   flag2Cnt = (int*)alloc(256);
  size_t zbytes = (size_t)(p - zbase);
  float4* flags  = (float4*)alloc((size_t)FLAGCAP*16);
  float4* flags2 = (float4*)alloc((size_t)FLAG2CAP*16);
  float* cur0 = (float*)alloc((size_t)NN*DD*4);

  // one-time prep (per call; inputs restored each replay)
  k_init<<<NN + 832, 256, 0, stream>>>(adj, adjw, wq, wk, wv, g1w, gc_w,
      qkvTh, qkvTl, g1wTh, g1wTl, gcwTh, gcwTl);

  const float* Ecur = embed;
  for (int l = 0; l < 2; l++){
    k_prep<<<2560, 256, 0, stream>>>(Ecur, nrm64, Enh, Enl, EhiT, EloT,
        qkvTh, qkvTl, bq, bk, bv, Qh, Khb, VhT, VloT);
    hipMemsetAsync(zbase, 0, zbytes, stream);
    if (l == 0)
      k_fused<0><<<(NN/BM)*CSPLIT, 256, 0, stream>>>(adjw, Enh, Enl, Qh, Khb,
          EhiT, EloT, VhT, VloT, Nsum, Bsum, cntN, denB,
          flagCnt, flags, flag2Cnt, flags2);
    else
      k_fused<1><<<(NN/BM)*CSPLIT, 256, 0, stream>>>(adjw, Enh, Enl, Qh, Khb,
          EhiT, EloT, VhT, VloT, Nsum, Bsum, cntN, denB,
          flagCnt, flags, flag2Cnt, flags2);
    k_fix<<<768, 256, 0, stream>>>(Ecur, nrm64, EhiT, EloT, VhT, VloT,
        Qh, Khb, (l == 0) ? 1 : 0, flag2Cnt, flags2, flagCnt, flags,
        Psum, Nsum, Bsum, cntP, cntN, denB);
    k_mlp<<<512, 256, 0, stream>>>(Ecur, Psum, Bsum, Nsum, cntP, cntN, denB,
        g1wTh, g1wTl, g1b, g2w, g2b,
        gcwTh + l*128*128, gcwTl + l*128*128, gc_b + l*128,
        cur0, lw, l, (l == 0) ? cur0 : out);
    Ecur = (l == 0) ? cur0 : out;
  }
}

// Round 11
// 983.601 us; speedup vs baseline: 1.4469x; 1.0631x over previous
//
#include <hip/hip_runtime.h>
#include <stdint.h>

#define NN 8192
#define DD 128
#define ALPHA 0.7f
#define BETA 0.3f
#define LAM 0.1f
#define QSCALE 0.08838834764831845f  // 1/sqrt(128)
#define DELTA 3e-5f      // L2 band: 3-term sim error ~1.5e-5
#define DELTA_L1 9e-3f   // L1 band: >= hi-only sim hard bound 7.85e-3
#define FLAGCAP 262144
#define FLAG2CAP 1048576

typedef __attribute__((ext_vector_type(8))) short short8;
typedef __attribute__((ext_vector_type(4))) float f32x4;
typedef unsigned short ush;

__device__ __forceinline__ ush f2bf(float f){
  union { float f; unsigned u; } v; v.f = f;
  return (ush)((v.u + 0x7FFFu + ((v.u >> 16) & 1u)) >> 16);
}
__device__ __forceinline__ float bf2f(ush s){
  union { unsigned u; float f; } v; v.u = ((unsigned)s) << 16; return v.f;
}

// identical scalar QK dot used by BOTH k_fix branches (L1 mode) so that the
// sparse add and any later refine subtract use the exact same s.
__device__ __forceinline__ float qkdot(const ush* __restrict__ Qh,
                                       const ush* __restrict__ Kh,
                                       int i, int j, int lane){
  float q0 = bf2f(Qh[i*DD + lane]),      k0 = bf2f(Kh[j*DD + lane]);
  float q1 = bf2f(Qh[i*DD + 64 + lane]), k1 = bf2f(Kh[j*DD + 64 + lane]);
  float s = q0*k0 + q1*k1;
  #pragma unroll
  for (int m = 32; m; m >>= 1) s += __shfl_xor(s, m, 64);
  return s;
}

// ---------------- one-time init: adjacency pack | weight transposes ----------------
// R18: weights written in FRAGMENT-MAJOR layout. For a B^T matrix [Nout][K], the
// 16x32 MFMA tile (nfrow, kk) is stored contiguously at tile*512 elements, with
// lane (quad*16+l15) owning 8 elements at lane*8 (element j <-> k = kk*32+quad*8+j).
// Consumers then issue ONE coalesced 1KB load per fragment instead of touching 64
// scattered cache lines.
__global__ void k_init(const float* __restrict__ adj, unsigned* __restrict__ adjw,
                       const float* __restrict__ wq, const float* __restrict__ wk,
                       const float* __restrict__ wv, const float* __restrict__ g1w,
                       const float* __restrict__ gcw,
                       ush* __restrict__ qkvTh, ush* __restrict__ qkvTl,
                       ush* __restrict__ g1wTh, ush* __restrict__ g1wTl,
                       ush* __restrict__ gcwTh, ush* __restrict__ gcwTl){
  if (blockIdx.x < NN){
    int i = blockIdx.x, wave = threadIdx.x >> 6, lane = threadIdx.x & 63;
    for (int seg = wave; seg < 128; seg += 4){
      int j = seg*64 + lane;
      unsigned long long bm = __ballot(adj[(size_t)i*NN + j] != 0.0f);
      if (lane == 0)  adjw[i*256 + seg*2]     = (unsigned)bm;
      if (lane == 32) adjw[i*256 + seg*2 + 1] = (unsigned)(bm >> 32);
    }
    return;
  }
  int idx = (blockIdx.x - NN)*256 + threadIdx.x;
  const float* src; ush *dh, *dl; int K, Nout, li;
  if      (idx <  16384){ src=wq;        dh=qkvTh;        dl=qkvTl;        K=128; Nout=128; li=idx; }
  else if (idx <  32768){ src=wk;        dh=qkvTh+16384;  dl=qkvTl+16384;  K=128; Nout=128; li=idx-16384; }
  else if (idx <  49152){ src=wv;        dh=qkvTh+32768;  dl=qkvTl+32768;  K=128; Nout=128; li=idx-32768; }
  else if (idx < 180224){ src=g1w;       dh=g1wTh;        dl=g1wTl;        K=512; Nout=256; li=idx-49152; }
  else if (idx < 196608){ src=gcw;       dh=gcwTh;        dl=gcwTl;        K=128; Nout=128; li=idx-180224; }
  else if (idx < 212992){ src=gcw+16384; dh=gcwTh+16384;  dl=gcwTl+16384;  K=128; Nout=128; li=idx-196608; }
  else return;
  int k = li / Nout, n = li - k*Nout;
  float v = src[li];
  ush h = f2bf(v);
  int nfrow = n >> 4, kk = k >> 5;
  int lanew = ((k >> 3) & 3)*16 + (n & 15);
  int dst = (nfrow*(K >> 5) + kk)*512 + lanew*8 + (k & 7);
  dh[dst] = h;
  dl[dst] = f2bf(v - bf2f(h));
}

// ---------------- merged per-layer prep: norm | transsplit | qkv (block-range) ----------------
// R18: qkv section now 512 blocks x 16 rows (2 blocks/CU) with fragment-major
// coalesced weight loads.
__global__ void k_prep(const float* __restrict__ E, double* __restrict__ nrm64,
                       ush* __restrict__ Enh, ush* __restrict__ Enl,
                       ush* __restrict__ EhiT, ush* __restrict__ EloT,
                       const ush* __restrict__ BtH, const ush* __restrict__ BtL,
                       const float* __restrict__ bq, const float* __restrict__ bk,
                       const float* __restrict__ bv,
                       ush* __restrict__ Qh, ush* __restrict__ Kh,
                       ush* __restrict__ VhT, ush* __restrict__ VloT){
  __shared__ float t[64][65];
  __shared__ float sV[128*17];
  int bid = blockIdx.x, tid = threadIdx.x;
  if (bid < 2048){
    // ---- norm: 4 rows/block ----
    int i = bid*4 + (tid >> 6);
    int l = tid & 63;
    float v0 = E[i*DD + l], v1 = E[i*DD + 64 + l];
    double ss = (double)v0*(double)v0 + (double)v1*(double)v1;
    #pragma unroll
    for (int m = 32; m; m >>= 1) ss += __shfl_xor(ss, m, 64);
    double nr = sqrt(ss); if (nr < 1e-8) nr = 1e-8;
    float inv = (float)(1.0 / nr);
    float n0 = v0*inv, n1 = v1*inv;
    ush h0 = f2bf(n0), h1 = f2bf(n1);
    Enh[i*DD + l] = h0;       Enh[i*DD + 64 + l] = h1;
    Enl[i*DD + l] = f2bf(n0 - bf2f(h0));
    Enl[i*DD + 64 + l] = f2bf(n1 - bf2f(h1));
    if (l == 0) nrm64[i] = nr;
  } else if (bid < 2304){
    // ---- transsplit: fp32 [8192,128] -> hi/lo bf16 T [128,8192] ----
    int lin = bid - 2048;
    int r0 = (lin >> 1) * 64, c0 = (lin & 1) * 64;
    for (int idx = tid; idx < 4096; idx += 256){
      int r = idx >> 6, c = idx & 63;
      t[r][c] = E[(r0 + r)*DD + c0 + c];
    }
    __syncthreads();
    for (int idx = tid; idx < 4096; idx += 256){
      int c = idx >> 6, r = idx & 63;
      float v = t[r][c];
      ush h = f2bf(v);
      EhiT[(size_t)(c0 + c)*NN + r0 + r] = h;
      EloT[(size_t)(c0 + c)*NN + r0 + r] = f2bf(v - bf2f(h));
    }
  } else {
    // ---- qkv: 16 rows/block; 4 waves x 6 nf; V transposed+split via LDS ----
    int lane = tid & 63, wave = tid >> 6;
    int l15 = lane & 15, quad = lane >> 4;
    int rowblk = (bid - 2304) * 16;
    int nf0 = wave*6;
    f32x4 acc[6];
    #pragma unroll
    for (int i = 0; i < 6; i++){ f32x4 z = {0.f,0.f,0.f,0.f}; acc[i] = z; }
    #pragma unroll
    for (int kk = 0; kk < 4; kk++){
      const float* ap = &E[(rowblk + l15)*DD + kk*32 + quad*8];
      short8 ah, al;
      #pragma unroll
      for (int j = 0; j < 8; j++){
        float v = ap[j];
        ush h = f2bf(v);
        ah[j] = (short)h; al[j] = (short)f2bf(v - bf2f(h));
      }
      #pragma unroll
      for (int i = 0; i < 6; i++){
        int bo = ((nf0 + i)*4 + kk)*512 + lane*8;
        short8 bh = *(const short8*)&BtH[bo];
        short8 bl = *(const short8*)&BtL[bo];
        acc[i] = __builtin_amdgcn_mfma_f32_16x16x32_bf16(ah, bh, acc[i], 0, 0, 0);
        acc[i] = __builtin_amdgcn_mfma_f32_16x16x32_bf16(al, bh, acc[i], 0, 0, 0);
        acc[i] = __builtin_amdgcn_mfma_f32_16x16x32_bf16(ah, bl, acc[i], 0, 0, 0);
      }
    }
    #pragma unroll
    for (int i = 0; i < 6; i++){
      int nfg = nf0 + i;
      int grp = nfg >> 3;
      int col = (nfg & 7)*16 + l15;
      float b = (grp == 0) ? bq[col] : (grp == 1) ? bk[col] : bv[col];
      #pragma unroll
      for (int r = 0; r < 4; r++){
        int row = rowblk + quad*4 + r;
        float v = acc[i][r] + b;
        if (grp == 0)      Qh[row*DD + col] = f2bf(v * QSCALE);
        else if (grp == 1) Kh[row*DD + col] = f2bf(v);
        else               sV[col*17 + (row - rowblk)] = v;
      }
    }
    __syncthreads();
    int feat = tid >> 1, rh = (tid & 1)*8;
    ush hh[8], ll[8];
    #pragma unroll
    for (int j = 0; j < 8; j++){
      float v = sV[feat*17 + rh + j];
      ush h = f2bf(v);
      hh[j] = h; ll[j] = f2bf(v - bf2f(h));
    }
    size_t go = (size_t)feat*NN + rowblk + rh;
    *(uint4*)&VhT [go] = *(const uint4*)&hh[0];
    *(uint4*)&VloT[go] = *(const uint4*)&ll[0];
  }
}

// ---------------- fused MLP: g1 GEMM -> (LDS h) -> gate/fusion/gc GEMM ----------------
// R18: fragment-major coalesced weight loads (g1T tiles: nf*16+kk of 16; gcT: nf*4+kk).
__global__ void k_mlp(const float* __restrict__ E, const float* __restrict__ P,
                      const float* __restrict__ B, const float* __restrict__ N,
                      const float* __restrict__ cntP, const float* __restrict__ cntN,
                      const float* __restrict__ denB,
                      const ush* __restrict__ g1Th, const ush* __restrict__ g1Tl,
                      const float* __restrict__ g1b,
                      const float* __restrict__ g2w, const float* __restrict__ g2b,
                      const ush* __restrict__ gcTh, const ush* __restrict__ gcTl,
                      const float* __restrict__ gcb,
                      const float* __restrict__ prevC, const float* __restrict__ lwv,
                      int dofinal, float* __restrict__ out){
  __shared__ float sH[16*260];
  int tid = threadIdx.x, lane = tid & 63, wave = tid >> 6;
  int l15 = lane & 15, quad = lane >> 4;
  int row16 = blockIdx.x*16;
  int row = row16 + l15;
  float cp = cntP[row], cn = cntN[row], dn = denB[row];
  // ---- phase 1: g1 (4-nf waves over 256 cols) ----
  {
    int nf0 = wave*4;
    float rs[4] = {1.f, 1.f/fmaxf(cp,1.f), (dn > 0.5f) ? (1.f/dn) : 0.f, LAM/fmaxf(cn,1.f)};
    const float* bases[4] = {E, P, B, N};
    f32x4 acc[4];
    #pragma unroll
    for (int nf = 0; nf < 4; nf++){ f32x4 z = {0.f,0.f,0.f,0.f}; acc[nf] = z; }
    #pragma unroll
    for (int kk = 0; kk < 16; kk++){
      const float* ap = &bases[kk>>2][row*DD + (kk&3)*32 + quad*8];
      float sc = rs[kk>>2];
      short8 ah, al;
      #pragma unroll
      for (int j = 0; j < 8; j++){
        float v = ap[j] * sc;
        ush h = f2bf(v);
        ah[j] = (short)h; al[j] = (short)f2bf(v - bf2f(h));
      }
      #pragma unroll
      for (int nf = 0; nf < 4; nf++){
        int bo = ((nf0 + nf)*16 + kk)*512 + lane*8;
        short8 bh = *(const short8*)&g1Th[bo];
        short8 bl = *(const short8*)&g1Tl[bo];
        acc[nf] = __builtin_amdgcn_mfma_f32_16x16x32_bf16(ah, bh, acc[nf], 0, 0, 0);
        acc[nf] = __builtin_amdgcn_mfma_f32_16x16x32_bf16(al, bh, acc[nf], 0, 0, 0);
        acc[nf] = __builtin_amdgcn_mfma_f32_16x16x32_bf16(ah, bl, acc[nf], 0, 0, 0);
      }
    }
    #pragma unroll
    for (int nf = 0; nf < 4; nf++){
      int col = (nf0 + nf)*16 + l15;
      float b = g1b[col];
      #pragma unroll
      for (int r = 0; r < 4; r++)
        sH[(quad*4 + r)*260 + col] = fmaxf(acc[nf][r] + b, 0.f);
    }
  }
  __syncthreads();
  // ---- phase 2: gate + fusion + gc GEMM (2-nf waves over 128 cols) ----
  {
    int nf0 = wave*2;
    float l0=0,l1=0,l2=0,l3=0;
    #pragma unroll
    for (int i = 0; i < 16; i++){
      float4 hv = *(const float4*)&sH[l15*260 + quad*64 + i*4];
      float hvv[4] = {hv.x, hv.y, hv.z, hv.w};
      #pragma unroll
      for (int j = 0; j < 4; j++){
        float4 w4 = *(const float4*)&g2w[(quad*64 + i*4 + j)*4];
        l0 = fmaf(hvv[j], w4.x, l0); l1 = fmaf(hvv[j], w4.y, l1);
        l2 = fmaf(hvv[j], w4.z, l2); l3 = fmaf(hvv[j], w4.w, l3);
      }
    }
    l0 += __shfl_xor(l0,16,64); l0 += __shfl_xor(l0,32,64);
    l1 += __shfl_xor(l1,16,64); l1 += __shfl_xor(l1,32,64);
    l2 += __shfl_xor(l2,16,64); l2 += __shfl_xor(l2,32,64);
    l3 += __shfl_xor(l3,16,64); l3 += __shfl_xor(l3,32,64);
    l0 += g2b[0]; l1 += g2b[1]; l2 += g2b[2]; l3 += g2b[3];
    float mx = fmaxf(fmaxf(l0,l1), fmaxf(l2,l3));
    float e0 = __expf(l0-mx), e1 = __expf(l1-mx), e2 = __expf(l2-mx), e3 = __expf(l3-mx);
    float inv = 1.f/(e0+e1+e2+e3);
    float g0 = e0*inv, g1v = e1*inv, g2v = e2*inv, g3 = e3*inv;
    bool any = (cp + cn > 0.5f) || (dn > 0.5f);
    float pscl = g1v/fmaxf(cp,1.f);
    float bscl = (dn > 0.5f) ? (g2v/dn) : 0.f;
    float nscl = LAM*g3/fmaxf(cn,1.f);
    f32x4 acc[2];
    #pragma unroll
    for (int nf = 0; nf < 2; nf++){ f32x4 z = {0.f,0.f,0.f,0.f}; acc[nf] = z; }
    #pragma unroll
    for (int kk = 0; kk < 4; kk++){
      int koff = row*DD + kk*32 + quad*8;
      short8 ah, al;
      #pragma unroll
      for (int j = 0; j < 8; j++){
        float ev = E[koff + j];
        float v = any ? (g0*ev + pscl*P[koff+j] + bscl*B[koff+j] + nscl*N[koff+j]) : ev;
        ush h = f2bf(v);
        ah[j] = (short)h; al[j] = (short)f2bf(v - bf2f(h));
      }
      #pragma unroll
      for (int nf = 0; nf < 2; nf++){
        int bo = ((nf0 + nf)*4 + kk)*512 + lane*8;
        short8 bh = *(const short8*)&gcTh[bo];
        short8 bl = *(const short8*)&gcTl[bo];
        acc[nf] = __builtin_amdgcn_mfma_f32_16x16x32_bf16(ah, bh, acc[nf], 0, 0, 0);
        acc[nf] = __builtin_amdgcn_mfma_f32_16x16x32_bf16(al, bh, acc[nf], 0, 0, 0);
        acc[nf] = __builtin_amdgcn_mfma_f32_16x16x32_bf16(ah, bl, acc[nf], 0, 0, 0);
      }
    }
    float we0 = 0.5f, we1 = 0.5f;
    if (dofinal){
      float a0 = lwv[0], a1 = lwv[1];
      float mw = fmaxf(a0, a1);
      float x0 = __expf(a0-mw), x1 = __expf(a1-mw);
      float iv = 1.f/(x0+x1);
      we0 = x0*iv; we1 = x1*iv;
    }
    #pragma unroll
    for (int nf = 0; nf < 2; nf++){
      int col = (nf0 + nf)*16 + l15;
      float b = gcb[col];
      #pragma unroll
      for (int r = 0; r < 4; r++){
        int rr = row16 + quad*4 + r;
        float val = fmaxf(acc[nf][r] + b, 0.f);
        if (dofinal) val = we0*prevC[rr*DD + col] + we1*val;
        out[rr*DD + col] = val;
      }
    }
  }
}

// ---------------- fused sim/classify/aggregate (R7 schedule FROZEN; R15 config) ----------------
// Untouched by R18 (byte-identical schedule/addressing; doesn't use weight arrays).
#define BM 64
#define BN 32
#define CSPLIT 4
#define CCHUNK (NN/CSPLIT)
#define NTILES (CCHUNK/BN)
#define RSTRIDE 136
#define FSTRIDE 80
#define MSTRIDE 80

template<int DENSEB>
__launch_bounds__(256, 2)
__global__ void k_fused(const unsigned* __restrict__ adjw,
    const ush* __restrict__ Enh, const ush* __restrict__ Enl,
    const ush* __restrict__ Qh,  const ush* __restrict__ Kh,
    const ush* __restrict__ EhiT, const ush* __restrict__ EloT,
    const ush* __restrict__ VhT,  const ush* __restrict__ VloT,
    float* __restrict__ Nsum, float* __restrict__ Bsum,
    float* __restrict__ cntN, float* __restrict__ denB,
    int* __restrict__ flagCnt, float4* __restrict__ flags,
    int* __restrict__ flag2Cnt, float4* __restrict__ flags2)
{
  __shared__ __attribute__((aligned(16))) ush sEnh[32*RSTRIDE];
  __shared__ __attribute__((aligned(16))) ush sEnl[DENSEB ? 32*RSTRIDE : 16];
  __shared__ __attribute__((aligned(16))) ush sKh [DENSEB ? 32*RSTRIDE : 16];
  __shared__ __attribute__((aligned(16))) ush sE2 [128*FSTRIDE];
  __shared__ __attribute__((aligned(16))) ush sV2 [DENSEB ? 128*FSTRIDE : 16];
  __shared__ __attribute__((aligned(16))) ush sM  [4][16*MSTRIDE];

  const float del = DENSEB ? DELTA : DELTA_L1;
  int tid = threadIdx.x, lane = tid & 63, wave = tid >> 6;
  int l15 = lane & 15, quad = lane >> 4;
  int rowblk = blockIdx.x >> 2, split = blockIdx.x & 3;
  int row0 = rowblk * BM + wave * 16;
  int col0 = split * CCHUNK;

  short8 bEnh[4], bEnl[4], bQ[4];
  #pragma unroll
  for (int kf = 0; kf < 4; kf++){
    int go = (row0 + l15)*DD + kf*32 + quad*8;
    bEnh[kf] = *(const short8*)&Enh[go];
    if (DENSEB){
      bEnl[kf] = *(const short8*)&Enl[go];
      bQ[kf] = *(const short8*)&Qh[go];
    }
  }

  f32x4 accN[8], accB[DENSEB ? 8 : 1];
  #pragma unroll
  for (int nf = 0; nf < 8; nf++){ f32x4 z = {0.f,0.f,0.f,0.f}; accN[nf]=z; }
  if (DENSEB){
    #pragma unroll
    for (int nf = 0; nf < 8; nf++){ f32x4 z = {0.f,0.f,0.f,0.f}; accB[nf]=z; }
  }
  float cnL = 0.f, dbL = 0.f;

  int f0 = tid >> 2,        n0 = (tid & 3)*8;
  int f1 = (tid+256) >> 2,  n1 = ((tid+256) & 3)*8;
  uint4 pEh0, pEh1, pVh0, pVh1;
  {
    size_t g0 = (size_t)f0*NN + col0 + n0, g1 = (size_t)f1*NN + col0 + n1;
    pEh0 = *(const uint4*)&EhiT[g0]; pEh1 = *(const uint4*)&EhiT[g1];
    if (DENSEB){
      pVh0 = *(const uint4*)&VhT [g0]; pVh1 = *(const uint4*)&VhT [g1];
    }
  }
  int rr0 = tid >> 4,       ro0 = (tid & 15)*8;
  int rr1 = (tid+256) >> 4, ro1 = ((tid+256) & 15)*8;

  for (int t = 0; t < NTILES; t++){
    int c0 = col0 + t*BN;
    __syncthreads();
    *(uint4*)&sE2[f0*FSTRIDE + n0] = pEh0;  *(uint4*)&sE2[f1*FSTRIDE + n1] = pEh1;
    if (DENSEB){
      *(uint4*)&sV2[f0*FSTRIDE + n0] = pVh0;  *(uint4*)&sV2[f1*FSTRIDE + n1] = pVh1;
    }
    {
      uint4 a0 = *(const uint4*)&Enh[(c0 + rr0)*DD + ro0];
      uint4 a1 = *(const uint4*)&Enh[(c0 + rr1)*DD + ro1];
      *(uint4*)&sEnh[rr0*RSTRIDE + ro0] = a0;  *(uint4*)&sEnh[rr1*RSTRIDE + ro1] = a1;
      if (DENSEB){
        uint4 b0 = *(const uint4*)&Enl[(c0 + rr0)*DD + ro0];
        uint4 b1 = *(const uint4*)&Enl[(c0 + rr1)*DD + ro1];
        uint4 k0 = *(const uint4*)&Kh [(c0 + rr0)*DD + ro0];
        uint4 k1 = *(const uint4*)&Kh [(c0 + rr1)*DD + ro1];
        *(uint4*)&sEnl[rr0*RSTRIDE + ro0] = b0;  *(uint4*)&sEnl[rr1*RSTRIDE + ro1] = b1;
        *(uint4*)&sKh [rr0*RSTRIDE + ro0] = k0;  *(uint4*)&sKh [rr1*RSTRIDE + ro1] = k1;
      }
    }
    __syncthreads();
    if (t + 1 < NTILES){
      int c1 = c0 + BN;
      size_t g0 = (size_t)f0*NN + c1 + n0, g1 = (size_t)f1*NN + c1 + n1;
      pEh0 = *(const uint4*)&EhiT[g0]; pEh1 = *(const uint4*)&EhiT[g1];
      if (DENSEB){
        pVh0 = *(const uint4*)&VhT [g0]; pVh1 = *(const uint4*)&VhT [g1];
      }
    }
    unsigned aw = adjw[(row0 + l15)*256 + (c0 >> 5)];

    f32x4 simT[2], svT[2];
    { f32x4 z = {0.f,0.f,0.f,0.f}; simT[0]=z; simT[1]=z; svT[0]=z; svT[1]=z; }
    #pragma unroll
    for (int f = 0; f < 2; f++){
      #pragma unroll
      for (int kf = 0; kf < 4; kf++){
        int la = (f*16 + l15)*RSTRIDE + kf*32 + quad*8;
        short8 ch = *(const short8*)&sEnh[la];
        simT[f] = __builtin_amdgcn_mfma_f32_16x16x32_bf16(ch, bEnh[kf], simT[f],0,0,0);
        if (DENSEB){
          short8 cl = *(const short8*)&sEnl[la];
          short8 ck = *(const short8*)&sKh [la];
          simT[f] = __builtin_amdgcn_mfma_f32_16x16x32_bf16(cl, bEnh[kf], simT[f],0,0,0);
          simT[f] = __builtin_amdgcn_mfma_f32_16x16x32_bf16(ch, bEnl[kf], simT[f],0,0,0);
          svT [f] = __builtin_amdgcn_mfma_f32_16x16x32_bf16(ck, bQ  [kf], svT [f],0,0,0);
        }
      }
    }
    ushort4 ehv[2];
    unsigned flagb = 0, spb = 0;
    #pragma unroll
    for (int f = 0; f < 2; f++){
      ush vn2[4], veh[4];
      #pragma unroll
      for (int r = 0; r < 4; r++){
        int cbit = f*16 + quad*4 + r;
        bool nbr = (aw >> cbit) & 1u;
        float c = simT[f][r];
        bool pos = nbr && (c >= ALPHA);
        bool neg = nbr && (c <= BETA);
        bool bnd = nbr && !pos && !neg;
        vn2[r] = neg ? (ush)0x3F80 : (ush)0;
        cnL += neg ? 1.f : 0.f;
        if (DENSEB){
          float e = bnd ? __expf(svT[f][r]) : 0.f;
          veh[r] = f2bf(e);
          dbL += e;
        }
        if (nbr && (fabsf(c - ALPHA) < del || fabsf(c - BETA) < del))
          flagb |= 1u << (f*4 + r);
        if (pos || (!DENSEB && bnd))
          spb |= 1u << (f*4 + r);
      }
      int mb = l15*MSTRIDE + f*16 + quad*4;
      *(ushort4*)&sM[wave][mb] = make_ushort4(vn2[0],vn2[1],vn2[2],vn2[3]);
      if (DENSEB)
        ehv[f] = make_ushort4(veh[0],veh[1],veh[2],veh[3]);
    }
    if (__ballot((flagb | spb) != 0)){
      #pragma unroll
      for (int f = 0; f < 2; f++){
        #pragma unroll
        for (int r = 0; r < 4; r++){
          int bit = f*4 + r;
          bool fl = (flagb >> bit) & 1u;
          unsigned long long bm = __ballot(fl);
          if (bm){
            int leader = __ffsll((long long)bm) - 1;
            int base = 0;
            if (lane == leader) base = atomicAdd(flagCnt, __popcll(bm));
            base = __shfl(base, leader, 64);
            if (fl){
              int id = base + __popcll(bm & ((1ull << lane) - 1ull));
              if (id < FLAGCAP){
                float4 rec;
                rec.x = __int_as_float(row0 + l15);
                rec.y = __int_as_float(c0 + f*16 + quad*4 + r);
                rec.z = simT[f][r];
                rec.w = DENSEB ? svT[f][r] : 0.f;
                flags[id] = rec;
              }
            }
          }
          bool f2 = (spb >> bit) & 1u;
          unsigned long long bm2 = __ballot(f2);
          if (bm2){
            int leader = __ffsll((long long)bm2) - 1;
            int base = 0;
            if (lane == leader) base = atomicAdd(flag2Cnt, __popcll(bm2));
            base = __shfl(base, leader, 64);
            if (f2){
              int id = base + __popcll(bm2 & ((1ull << lane) - 1ull));
              if (id < FLAG2CAP){
                float c = simT[f][r];
                int j = c0 + f*16 + quad*4 + r;
                int cls = (c >= ALPHA) ? 0 : 1;
                float4 rec;
                rec.x = __int_as_float(row0 + l15);
                rec.y = __int_as_float(j | (cls << 16));
                rec.z = c;
                rec.w = DENSEB ? svT[f][r] : 0.f;
                flags2[id] = rec;
              }
            }
          }
        }
      }
    }
    {
      short8 mNeg = *(const short8*)&sM[wave][l15*MSTRIDE + quad*8];
      #pragma unroll
      for (int nf = 0; nf < 8; nf++){
        int so = (nf*16 + l15)*FSTRIDE + quad*8;
        short8 eth = *(const short8*)&sE2[so];
        accN[nf] = __builtin_amdgcn_mfma_f32_16x16x32_bf16(mNeg, eth, accN[nf],0,0,0);
      }
    }
    if (DENSEB){
      int mb0 = l15*MSTRIDE + quad*4;
      *(ushort4*)&sM[wave][mb0]      = ehv[0];
      *(ushort4*)&sM[wave][mb0 + 16] = ehv[1];
      short8 mEh = *(const short8*)&sM[wave][l15*MSTRIDE + quad*8];
      #pragma unroll
      for (int nf = 0; nf < 8; nf++){
        int so = (nf*16 + l15)*FSTRIDE + quad*8;
        short8 vth = *(const short8*)&sV2[so];
        accB[nf] = __builtin_amdgcn_mfma_f32_16x16x32_bf16(mEh, vth, accB[nf],0,0,0);
      }
    }
  }
  #pragma unroll
  for (int nf = 0; nf < 8; nf++){
    int col = nf*16 + l15;
    #pragma unroll
    for (int r = 0; r < 4; r++){
      int row = row0 + quad*4 + r;
      atomicAdd(&Nsum[row*DD + col], accN[nf][r]);
      if (DENSEB) atomicAdd(&Bsum[row*DD + col], accB[nf][r]);
    }
  }
  cnL += __shfl_xor(cnL, 16, 64); cnL += __shfl_xor(cnL, 32, 64);
  if (DENSEB){ dbL += __shfl_xor(dbL, 16, 64); dbL += __shfl_xor(dbL, 32, 64); }
  if (quad == 0){
    atomicAdd(&cntN[row0 + l15], cnL);
    if (DENSEB) atomicAdd(&denB[row0 + l15], dbL);
  }
}

// ---------------- merged sparse replay + fp64 refine (commuting atomics) ----------------
// Class-dependent formulas (mirror the dense paths exactly):
//   neg (dense, both layers): ev_neg = hi-only
//   pos (sparse, both layers): ev_pos = hi+lo
//   bnd L1 (dotmode=1, sparse): bv = ehf*vh + (elf*vh + ehf*vl)  (3-term)
//   bnd L2 (dotmode=0, dense):  bv = ehf*vh                      (1-term)
__global__ void k_fix(const float* __restrict__ E, const double* __restrict__ nrm64,
    const ush* __restrict__ EhiT, const ush* __restrict__ EloT,
    const ush* __restrict__ VhT,  const ush* __restrict__ VloT,
    const ush* __restrict__ Qh,   const ush* __restrict__ Kh, int dotmode,
    const int* __restrict__ flag2Cnt, const float4* __restrict__ flags2,
    const int* __restrict__ flagCnt,  const float4* __restrict__ flags,
    float* __restrict__ Psum, float* __restrict__ Nsum, float* __restrict__ Bsum,
    float* __restrict__ cntP, float* __restrict__ cntN, float* __restrict__ denB)
{
  int lane = threadIdx.x & 63;
  if (blockIdx.x < 256){
    // ---- sparse pos/bnd replay ----
    int cnt = *flag2Cnt; if (cnt > FLAG2CAP) cnt = FLAG2CAP;
    int gw = (blockIdx.x * blockDim.x + threadIdx.x) >> 6;
    int nw = (256 * blockDim.x) >> 6;
    for (int idx = gw; idx < cnt; idx += nw){
      float4 rec = flags2[idx];
      int i = __float_as_int(rec.x);
      int jraw = __float_as_int(rec.y);
      int j = jraw & 0xFFFF, cls = jraw >> 16;
      if (cls == 0){
        #pragma unroll
        for (int h = 0; h < 2; h++){
          int d = lane + h*64;
          float ev = bf2f(EhiT[(size_t)d*NN + j]) + bf2f(EloT[(size_t)d*NN + j]);
          atomicAdd(&Psum[i*DD + d], ev);
        }
        if (lane == 0) atomicAdd(&cntP[i], 1.f);
      } else {
        float s = dotmode ? qkdot(Qh, Kh, i, j, lane) : rec.w;
        float e = __expf(s);
        float ehf = bf2f(f2bf(e));
        float elf = bf2f(f2bf(e - ehf));
        #pragma unroll
        for (int h = 0; h < 2; h++){
          int d = lane + h*64;
          float vh = bf2f(VhT [(size_t)d*NN + j]);
          float bv = ehf*vh;
          if (dotmode) bv += elf*vh + ehf*bf2f(VloT[(size_t)d*NN + j]);
          atomicAdd(&Bsum[i*DD + d], bv);
        }
        if (lane == 0) atomicAdd(&denB[i], e);
      }
    }
  } else {
    // ---- fp64 boundary refinement ----
    int cnt = *flagCnt; if (cnt > FLAGCAP) cnt = FLAGCAP;
    int gw = ((blockIdx.x - 256) * blockDim.x + threadIdx.x) >> 6;
    int nw = (512 * blockDim.x) >> 6;
    for (int idx = gw; idx < cnt; idx += nw){
      float4 rec = flags[idx];
      int i = __float_as_int(rec.x), j = __float_as_int(rec.y);
      float c = rec.z;
      float ei0 = E[i*DD + lane], ei1 = E[i*DD + 64 + lane];
      float ej0 = E[j*DD + lane], ej1 = E[j*DD + 64 + lane];
      double d = (double)ei0*(double)ej0 + (double)ei1*(double)ej1;
      #pragma unroll
      for (int m = 32; m; m >>= 1) d += __shfl_xor(d, m, 64);
      double se = d / (nrm64[i]*nrm64[j]);
      int ce = (se >= (double)ALPHA) ? 0 : ((se <= (double)BETA) ? 1 : 2);
      int cc = (c >= ALPHA) ? 0 : ((c <= BETA) ? 1 : 2);
      if (ce == cc) continue;
      float s = dotmode ? qkdot(Qh, Kh, i, j, lane) : rec.w;
      float e = __expf(s);
      float ehf = bf2f(f2bf(e));
      float elf = bf2f(f2bf(e - ehf));
      #pragma unroll
      for (int h = 0; h < 2; h++){
        int dd2 = lane + h*64;
        float evh = bf2f(EhiT[(size_t)dd2*NN + j]);
        float evp = evh + bf2f(EloT[(size_t)dd2*NN + j]);  // pos: hi+lo
        float vh = bf2f(VhT[(size_t)dd2*NN + j]);
        float bv = ehf*vh;
        if (dotmode) bv += elf*vh + ehf*bf2f(VloT[(size_t)dd2*NN + j]);
        float subv = (cc==0) ? -evp : (cc==1) ? -evh : -bv;
        float* subA = (cc==0) ? Psum : (cc==1) ? Nsum : Bsum;
        atomicAdd(&subA[i*DD + dd2], subv);
        float addv = (ce==0) ? evp : (ce==1) ? evh : bv;
        float* addA = (ce==0) ? Psum : (ce==1) ? Nsum : Bsum;
        atomicAdd(&addA[i*DD + dd2], addv);
      }
      if (lane == 0){
        float* subC = (cc==0) ? cntP : (cc==1) ? cntN : denB;
        atomicAdd(&subC[i], (cc==2) ? -e : -1.f);
        float* addC = (ce==0) ? cntP : (ce==1) ? cntN : denB;
        atomicAdd(&addC[i], (ce==2) ?  e :  1.f);
      }
    }
  }
}

extern "C" void kernel_launch(void* const* d_in, const int* in_sizes, int n_in,
                              void* d_out, int out_size, void* d_ws, size_t ws_size,
                              hipStream_t stream){
  const float* adj   = (const float*)d_in[0];
  const float* embed = (const float*)d_in[1];
  const float* gc_w  = (const float*)d_in[2];
  const float* gc_b  = (const float*)d_in[3];
  const float* wq = (const float*)d_in[4];
  const float* bq = (const float*)d_in[5];
  const float* wk = (const float*)d_in[6];
  const float* bk = (const float*)d_in[7];
  const float* wv = (const float*)d_in[8];
  const float* bv = (const float*)d_in[9];
  const float* g1w = (const float*)d_in[10];
  const float* g1b = (const float*)d_in[11];
  const float* g2w = (const float*)d_in[12];
  const float* g2b = (const float*)d_in[13];
  const float* lw  = (const float*)d_in[14];
  float* out = (float*)d_out;

  char* p = (char*)d_ws;
  auto alloc = [&](size_t bytes)->void*{ void* r = (void*)p; p += (bytes + 255) & ~(size_t)255; return r; };
  ush* qkvTh = (ush*)alloc(384*128*2);  ush* qkvTl = (ush*)alloc(384*128*2);
  ush* g1wTh = (ush*)alloc(512*256*2);  ush* g1wTl = (ush*)alloc(512*256*2);
  ush* gcwTh = (ush*)alloc(2*128*128*2); ush* gcwTl = (ush*)alloc(2*128*128*2);
  unsigned* adjw = (unsigned*)alloc((size_t)NN*256*4);
  double* nrm64 = (double*)alloc(NN*8);
  ush* Enh  = (ush*)alloc((size_t)NN*DD*2);
  ush* Enl  = (ush*)alloc((size_t)NN*DD*2);
  ush* EhiT = (ush*)alloc((size_t)NN*DD*2);
  ush* EloT = (ush*)alloc((size_t)NN*DD*2);
  ush* Qh   = (ush*)alloc((size_t)NN*DD*2);
  ush* Khb  = (ush*)alloc((size_t)NN*DD*2);
  ush* VhT  = (ush*)alloc((size_t)NN*DD*2);
  ush* VloT = (ush*)alloc((size_t)NN*DD*2);
  char* zbase = p;
  float* Psum = (float*)alloc((size_t)NN*DD*4);
  float* Nsum = (float*)alloc((size_t)NN*DD*4);
  float* Bsum = (float*)alloc((size_t)NN*DD*4);
  float* cntP = (float*)alloc(NN*4);
  float* cntN = (float*)alloc(NN*4);
  float* denB = (float*)alloc(NN*4);
  int*   flagCnt  = (int*)alloc(256);
  int*   flag2Cnt = (int*)alloc(256);
  size_t zbytes = (size_t)(p - zbase);
  float4* flags  = (float4*)alloc((size_t)FLAGCAP*16);
  float4* flags2 = (float4*)alloc((size_t)FLAG2CAP*16);
  float* cur0 = (float*)alloc((size_t)NN*DD*4);

  // one-time prep (per call; inputs restored each replay)
  k_init<<<NN + 832, 256, 0, stream>>>(adj, adjw, wq, wk, wv, g1w, gc_w,
      qkvTh, qkvTl, g1wTh, g1wTl, gcwTh, gcwTl);

  const float* Ecur = embed;
  for (int l = 0; l < 2; l++){
    k_prep<<<2816, 256, 0, stream>>>(Ecur, nrm64, Enh, Enl, EhiT, EloT,
        qkvTh, qkvTl, bq, bk, bv, Qh, Khb, VhT, VloT);
    hipMemsetAsync(zbase, 0, zbytes, stream);
    if (l == 0)
      k_fused<0><<<(NN/BM)*CSPLIT, 256, 0, stream>>>(adjw, Enh, Enl, Qh, Khb,
          EhiT, EloT, VhT, VloT, Nsum, Bsum, cntN, denB,
          flagCnt, flags, flag2Cnt, flags2);
    else
      k_fused<1><<<(NN/BM)*CSPLIT, 256, 0, stream>>>(adjw, Enh, Enl, Qh, Khb,
          EhiT, EloT, VhT, VloT, Nsum, Bsum, cntN, denB,
          flagCnt, flags, flag2Cnt, flags2);
    k_fix<<<768, 256, 0, stream>>>(Ecur, nrm64, EhiT, EloT, VhT, VloT,
        Qh, Khb, (l == 0) ? 1 : 0, flag2Cnt, flags2, flagCnt, flags,
        Psum, Nsum, Bsum, cntP, cntN, denB);
    k_mlp<<<512, 256, 0, stream>>>(Ecur, Psum, Bsum, Nsum, cntP, cntN, denB,
        g1wTh, g1wTl, g1b, g2w, g2b,
        gcwTh + l*128*128, gcwTl + l*128*128, gc_b + l*128,
        cur0, lw, l, (l == 0) ? cur0 : out);
    Ecur = (l == 0) ? cur0 : out;
  }
}

// Round 12
// 980.396 us; speedup vs baseline: 1.4516x; 1.0033x over previous
//
#include <hip/hip_runtime.h>
#include <stdint.h>

#define NN 8192
#define DD 128
#define ALPHA 0.7f
#define BETA 0.3f
#define LAM 0.1f
#define QSCALE 0.08838834764831845f  // 1/sqrt(128)
#define DELTA 3e-5f      // L2 band: 3-term sim error ~1.5e-5
#define DELTA_L1 9e-3f   // L1 band: >= hi-only sim hard bound 7.85e-3
#define FLAGCAP 262144
#define FLAG2CAP 1048576

typedef __attribute__((ext_vector_type(8))) short short8;
typedef __attribute__((ext_vector_type(4))) float f32x4;
typedef unsigned short ush;

__device__ __forceinline__ ush f2bf(float f){
  union { float f; unsigned u; } v; v.f = f;
  return (ush)((v.u + 0x7FFFu + ((v.u >> 16) & 1u)) >> 16);
}
__device__ __forceinline__ float bf2f(ush s){
  union { unsigned u; float f; } v; v.u = ((unsigned)s) << 16; return v.f;
}

// identical scalar QK dot used by BOTH k_fix branches (L1 mode) so that the
// sparse add and any later refine subtract use the exact same s.
__device__ __forceinline__ float qkdot(const ush* __restrict__ Qh,
                                       const ush* __restrict__ Kh,
                                       int i, int j, int lane){
  float q0 = bf2f(Qh[i*DD + lane]),      k0 = bf2f(Kh[j*DD + lane]);
  float q1 = bf2f(Qh[i*DD + 64 + lane]), k1 = bf2f(Kh[j*DD + 64 + lane]);
  float s = q0*k0 + q1*k1;
  #pragma unroll
  for (int m = 32; m; m >>= 1) s += __shfl_xor(s, m, 64);
  return s;
}

// ---------------- one-time init: adjacency pack | weight transposes ----------------
// Fragment-major weight layout (R18): tile (nfrow, kk) of a [Nout][K] B^T matrix
// stored contiguously at tile*512, lane (quad*16+l15) owns 8 elems at lane*8
// (elem j <-> k = kk*32+quad*8+j). Consumers issue ONE coalesced 1KB load/fragment.
__global__ void k_init(const float* __restrict__ adj, unsigned* __restrict__ adjw,
                       const float* __restrict__ wq, const float* __restrict__ wk,
                       const float* __restrict__ wv, const float* __restrict__ g1w,
                       const float* __restrict__ gcw,
                       ush* __restrict__ qkvTh, ush* __restrict__ qkvTl,
                       ush* __restrict__ g1wTh, ush* __restrict__ g1wTl,
                       ush* __restrict__ gcwTh, ush* __restrict__ gcwTl){
  if (blockIdx.x < NN){
    int i = blockIdx.x, wave = threadIdx.x >> 6, lane = threadIdx.x & 63;
    for (int seg = wave; seg < 128; seg += 4){
      int j = seg*64 + lane;
      unsigned long long bm = __ballot(adj[(size_t)i*NN + j] != 0.0f);
      if (lane == 0)  adjw[i*256 + seg*2]     = (unsigned)bm;
      if (lane == 32) adjw[i*256 + seg*2 + 1] = (unsigned)(bm >> 32);
    }
    return;
  }
  int idx = (blockIdx.x - NN)*256 + threadIdx.x;
  const float* src; ush *dh, *dl; int K, Nout, li;
  if      (idx <  16384){ src=wq;        dh=qkvTh;        dl=qkvTl;        K=128; Nout=128; li=idx; }
  else if (idx <  32768){ src=wk;        dh=qkvTh+16384;  dl=qkvTl+16384;  K=128; Nout=128; li=idx-16384; }
  else if (idx <  49152){ src=wv;        dh=qkvTh+32768;  dl=qkvTl+32768;  K=128; Nout=128; li=idx-32768; }
  else if (idx < 180224){ src=g1w;       dh=g1wTh;        dl=g1wTl;        K=512; Nout=256; li=idx-49152; }
  else if (idx < 196608){ src=gcw;       dh=gcwTh;        dl=gcwTl;        K=128; Nout=128; li=idx-180224; }
  else if (idx < 212992){ src=gcw+16384; dh=gcwTh+16384;  dl=gcwTl+16384;  K=128; Nout=128; li=idx-196608; }
  else return;
  int k = li / Nout, n = li - k*Nout;
  float v = src[li];
  ush h = f2bf(v);
  int nfrow = n >> 4, kk = k >> 5;
  int lanew = ((k >> 3) & 3)*16 + (n & 15);
  int dst = (nfrow*(K >> 5) + kk)*512 + lanew*8 + (k & 7);
  dh[dst] = h;
  dl[dst] = f2bf(v - bf2f(h));
}

// ---------------- merged per-layer prep: norm | transsplit | qkv (block-range) ----------------
// R19: transsplit stores vectorized (8 consecutive r per thread -> uint4 stores;
// was 32 scalar 2B stores/thread). Values bit-identical.
__global__ void k_prep(const float* __restrict__ E, double* __restrict__ nrm64,
                       ush* __restrict__ Enh, ush* __restrict__ Enl,
                       ush* __restrict__ EhiT, ush* __restrict__ EloT,
                       const ush* __restrict__ BtH, const ush* __restrict__ BtL,
                       const float* __restrict__ bq, const float* __restrict__ bk,
                       const float* __restrict__ bv,
                       ush* __restrict__ Qh, ush* __restrict__ Kh,
                       ush* __restrict__ VhT, ush* __restrict__ VloT){
  __shared__ float t[64][65];
  __shared__ float sV[128*17];
  int bid = blockIdx.x, tid = threadIdx.x;
  if (bid < 2048){
    // ---- norm: 4 rows/block ----
    int i = bid*4 + (tid >> 6);
    int l = tid & 63;
    float v0 = E[i*DD + l], v1 = E[i*DD + 64 + l];
    double ss = (double)v0*(double)v0 + (double)v1*(double)v1;
    #pragma unroll
    for (int m = 32; m; m >>= 1) ss += __shfl_xor(ss, m, 64);
    double nr = sqrt(ss); if (nr < 1e-8) nr = 1e-8;
    float inv = (float)(1.0 / nr);
    float n0 = v0*inv, n1 = v1*inv;
    ush h0 = f2bf(n0), h1 = f2bf(n1);
    Enh[i*DD + l] = h0;       Enh[i*DD + 64 + l] = h1;
    Enl[i*DD + l] = f2bf(n0 - bf2f(h0));
    Enl[i*DD + 64 + l] = f2bf(n1 - bf2f(h1));
    if (l == 0) nrm64[i] = nr;
  } else if (bid < 2304){
    // ---- transsplit: fp32 [8192,128] -> hi/lo bf16 T [128,8192] ----
    int lin = bid - 2048;
    int r0 = (lin >> 1) * 64, c0 = (lin & 1) * 64;
    for (int idx = tid; idx < 4096; idx += 256){
      int r = idx >> 6, c = idx & 63;
      t[r][c] = E[(r0 + r)*DD + c0 + c];
    }
    __syncthreads();
    // 64 cols x 8 r-groups; each item emits 8 consecutive r as one uint4 pair
    for (int idx = tid; idx < 512; idx += 256){
      int c = idx >> 3, rg = (idx & 7)*8;
      ush hh[8], ll[8];
      #pragma unroll
      for (int j = 0; j < 8; j++){
        float v = t[rg + j][c];
        ush h = f2bf(v);
        hh[j] = h; ll[j] = f2bf(v - bf2f(h));
      }
      size_t go = (size_t)(c0 + c)*NN + r0 + rg;
      *(uint4*)&EhiT[go] = *(const uint4*)&hh[0];
      *(uint4*)&EloT[go] = *(const uint4*)&ll[0];
    }
  } else {
    // ---- qkv: 16 rows/block; 4 waves x 6 nf; V transposed+split via LDS ----
    int lane = tid & 63, wave = tid >> 6;
    int l15 = lane & 15, quad = lane >> 4;
    int rowblk = (bid - 2304) * 16;
    int nf0 = wave*6;
    f32x4 acc[6];
    #pragma unroll
    for (int i = 0; i < 6; i++){ f32x4 z = {0.f,0.f,0.f,0.f}; acc[i] = z; }
    #pragma unroll
    for (int kk = 0; kk < 4; kk++){
      const float* ap = &E[(rowblk + l15)*DD + kk*32 + quad*8];
      short8 ah, al;
      #pragma unroll
      for (int j = 0; j < 8; j++){
        float v = ap[j];
        ush h = f2bf(v);
        ah[j] = (short)h; al[j] = (short)f2bf(v - bf2f(h));
      }
      #pragma unroll
      for (int i = 0; i < 6; i++){
        int bo = ((nf0 + i)*4 + kk)*512 + lane*8;
        short8 bh = *(const short8*)&BtH[bo];
        short8 bl = *(const short8*)&BtL[bo];
        acc[i] = __builtin_amdgcn_mfma_f32_16x16x32_bf16(ah, bh, acc[i], 0, 0, 0);
        acc[i] = __builtin_amdgcn_mfma_f32_16x16x32_bf16(al, bh, acc[i], 0, 0, 0);
        acc[i] = __builtin_amdgcn_mfma_f32_16x16x32_bf16(ah, bl, acc[i], 0, 0, 0);
      }
    }
    #pragma unroll
    for (int i = 0; i < 6; i++){
      int nfg = nf0 + i;
      int grp = nfg >> 3;
      int col = (nfg & 7)*16 + l15;
      float b = (grp == 0) ? bq[col] : (grp == 1) ? bk[col] : bv[col];
      #pragma unroll
      for (int r = 0; r < 4; r++){
        int row = rowblk + quad*4 + r;
        float v = acc[i][r] + b;
        if (grp == 0)      Qh[row*DD + col] = f2bf(v * QSCALE);
        else if (grp == 1) Kh[row*DD + col] = f2bf(v);
        else               sV[col*17 + (row - rowblk)] = v;
      }
    }
    __syncthreads();
    int feat = tid >> 1, rh = (tid & 1)*8;
    ush hh[8], ll[8];
    #pragma unroll
    for (int j = 0; j < 8; j++){
      float v = sV[feat*17 + rh + j];
      ush h = f2bf(v);
      hh[j] = h; ll[j] = f2bf(v - bf2f(h));
    }
    size_t go = (size_t)feat*NN + rowblk + rh;
    *(uint4*)&VhT [go] = *(const uint4*)&hh[0];
    *(uint4*)&VloT[go] = *(const uint4*)&ll[0];
  }
}

// ---------------- fused MLP: g1 GEMM -> (LDS h) -> gate/fusion/gc GEMM ----------------
__global__ void k_mlp(const float* __restrict__ E, const float* __restrict__ P,
                      const float* __restrict__ B, const float* __restrict__ N,
                      const float* __restrict__ cntP, const float* __restrict__ cntN,
                      const float* __restrict__ denB,
                      const ush* __restrict__ g1Th, const ush* __restrict__ g1Tl,
                      const float* __restrict__ g1b,
                      const float* __restrict__ g2w, const float* __restrict__ g2b,
                      const ush* __restrict__ gcTh, const ush* __restrict__ gcTl,
                      const float* __restrict__ gcb,
                      const float* __restrict__ prevC, const float* __restrict__ lwv,
                      int dofinal, float* __restrict__ out){
  __shared__ float sH[16*260];
  int tid = threadIdx.x, lane = tid & 63, wave = tid >> 6;
  int l15 = lane & 15, quad = lane >> 4;
  int row16 = blockIdx.x*16;
  int row = row16 + l15;
  float cp = cntP[row], cn = cntN[row], dn = denB[row];
  // ---- phase 1: g1 (4-nf waves over 256 cols) ----
  {
    int nf0 = wave*4;
    float rs[4] = {1.f, 1.f/fmaxf(cp,1.f), (dn > 0.5f) ? (1.f/dn) : 0.f, LAM/fmaxf(cn,1.f)};
    const float* bases[4] = {E, P, B, N};
    f32x4 acc[4];
    #pragma unroll
    for (int nf = 0; nf < 4; nf++){ f32x4 z = {0.f,0.f,0.f,0.f}; acc[nf] = z; }
    #pragma unroll
    for (int kk = 0; kk < 16; kk++){
      const float* ap = &bases[kk>>2][row*DD + (kk&3)*32 + quad*8];
      float sc = rs[kk>>2];
      short8 ah, al;
      #pragma unroll
      for (int j = 0; j < 8; j++){
        float v = ap[j] * sc;
        ush h = f2bf(v);
        ah[j] = (short)h; al[j] = (short)f2bf(v - bf2f(h));
      }
      #pragma unroll
      for (int nf = 0; nf < 4; nf++){
        int bo = ((nf0 + nf)*16 + kk)*512 + lane*8;
        short8 bh = *(const short8*)&g1Th[bo];
        short8 bl = *(const short8*)&g1Tl[bo];
        acc[nf] = __builtin_amdgcn_mfma_f32_16x16x32_bf16(ah, bh, acc[nf], 0, 0, 0);
        acc[nf] = __builtin_amdgcn_mfma_f32_16x16x32_bf16(al, bh, acc[nf], 0, 0, 0);
        acc[nf] = __builtin_amdgcn_mfma_f32_16x16x32_bf16(ah, bl, acc[nf], 0, 0, 0);
      }
    }
    #pragma unroll
    for (int nf = 0; nf < 4; nf++){
      int col = (nf0 + nf)*16 + l15;
      float b = g1b[col];
      #pragma unroll
      for (int r = 0; r < 4; r++)
        sH[(quad*4 + r)*260 + col] = fmaxf(acc[nf][r] + b, 0.f);
    }
  }
  __syncthreads();
  // ---- phase 2: gate + fusion + gc GEMM (2-nf waves over 128 cols) ----
  {
    int nf0 = wave*2;
    float l0=0,l1=0,l2=0,l3=0;
    #pragma unroll
    for (int i = 0; i < 16; i++){
      float4 hv = *(const float4*)&sH[l15*260 + quad*64 + i*4];
      float hvv[4] = {hv.x, hv.y, hv.z, hv.w};
      #pragma unroll
      for (int j = 0; j < 4; j++){
        float4 w4 = *(const float4*)&g2w[(quad*64 + i*4 + j)*4];
        l0 = fmaf(hvv[j], w4.x, l0); l1 = fmaf(hvv[j], w4.y, l1);
        l2 = fmaf(hvv[j], w4.z, l2); l3 = fmaf(hvv[j], w4.w, l3);
      }
    }
    l0 += __shfl_xor(l0,16,64); l0 += __shfl_xor(l0,32,64);
    l1 += __shfl_xor(l1,16,64); l1 += __shfl_xor(l1,32,64);
    l2 += __shfl_xor(l2,16,64); l2 += __shfl_xor(l2,32,64);
    l3 += __shfl_xor(l3,16,64); l3 += __shfl_xor(l3,32,64);
    l0 += g2b[0]; l1 += g2b[1]; l2 += g2b[2]; l3 += g2b[3];
    float mx = fmaxf(fmaxf(l0,l1), fmaxf(l2,l3));
    float e0 = __expf(l0-mx), e1 = __expf(l1-mx), e2 = __expf(l2-mx), e3 = __expf(l3-mx);
    float inv = 1.f/(e0+e1+e2+e3);
    float g0 = e0*inv, g1v = e1*inv, g2v = e2*inv, g3 = e3*inv;
    bool any = (cp + cn > 0.5f) || (dn > 0.5f);
    float pscl = g1v/fmaxf(cp,1.f);
    float bscl = (dn > 0.5f) ? (g2v/dn) : 0.f;
    float nscl = LAM*g3/fmaxf(cn,1.f);
    f32x4 acc[2];
    #pragma unroll
    for (int nf = 0; nf < 2; nf++){ f32x4 z = {0.f,0.f,0.f,0.f}; acc[nf] = z; }
    #pragma unroll
    for (int kk = 0; kk < 4; kk++){
      int koff = row*DD + kk*32 + quad*8;
      short8 ah, al;
      #pragma unroll
      for (int j = 0; j < 8; j++){
        float ev = E[koff + j];
        float v = any ? (g0*ev + pscl*P[koff+j] + bscl*B[koff+j] + nscl*N[koff+j]) : ev;
        ush h = f2bf(v);
        ah[j] = (short)h; al[j] = (short)f2bf(v - bf2f(h));
      }
      #pragma unroll
      for (int nf = 0; nf < 2; nf++){
        int bo = ((nf0 + nf)*4 + kk)*512 + lane*8;
        short8 bh = *(const short8*)&gcTh[bo];
        short8 bl = *(const short8*)&gcTl[bo];
        acc[nf] = __builtin_amdgcn_mfma_f32_16x16x32_bf16(ah, bh, acc[nf], 0, 0, 0);
        acc[nf] = __builtin_amdgcn_mfma_f32_16x16x32_bf16(al, bh, acc[nf], 0, 0, 0);
        acc[nf] = __builtin_amdgcn_mfma_f32_16x16x32_bf16(ah, bl, acc[nf], 0, 0, 0);
      }
    }
    float we0 = 0.5f, we1 = 0.5f;
    if (dofinal){
      float a0 = lwv[0], a1 = lwv[1];
      float mw = fmaxf(a0, a1);
      float x0 = __expf(a0-mw), x1 = __expf(a1-mw);
      float iv = 1.f/(x0+x1);
      we0 = x0*iv; we1 = x1*iv;
    }
    #pragma unroll
    for (int nf = 0; nf < 2; nf++){
      int col = (nf0 + nf)*16 + l15;
      float b = gcb[col];
      #pragma unroll
      for (int r = 0; r < 4; r++){
        int rr = row16 + quad*4 + r;
        float val = fmaxf(acc[nf][r] + b, 0.f);
        if (dofinal) val = we0*prevC[rr*DD + col] + we1*val;
        out[rr*DD + col] = val;
      }
    }
  }
}

// ---------------- fused sim/classify/aggregate (R7 schedule FROZEN; R15 config) ----------------
#define BM 64
#define BN 32
#define CSPLIT 4
#define CCHUNK (NN/CSPLIT)
#define NTILES (CCHUNK/BN)
#define RSTRIDE 136
#define FSTRIDE 80
#define MSTRIDE 80

template<int DENSEB>
__launch_bounds__(256, 2)
__global__ void k_fused(const unsigned* __restrict__ adjw,
    const ush* __restrict__ Enh, const ush* __restrict__ Enl,
    const ush* __restrict__ Qh,  const ush* __restrict__ Kh,
    const ush* __restrict__ EhiT, const ush* __restrict__ EloT,
    const ush* __restrict__ VhT,  const ush* __restrict__ VloT,
    float* __restrict__ Nsum, float* __restrict__ Bsum,
    float* __restrict__ cntN, float* __restrict__ denB,
    int* __restrict__ flagCnt, float4* __restrict__ flags,
    int* __restrict__ flag2Cnt, float4* __restrict__ flags2)
{
  __shared__ __attribute__((aligned(16))) ush sEnh[32*RSTRIDE];
  __shared__ __attribute__((aligned(16))) ush sEnl[DENSEB ? 32*RSTRIDE : 16];
  __shared__ __attribute__((aligned(16))) ush sKh [DENSEB ? 32*RSTRIDE : 16];
  __shared__ __attribute__((aligned(16))) ush sE2 [128*FSTRIDE];
  __shared__ __attribute__((aligned(16))) ush sV2 [DENSEB ? 128*FSTRIDE : 16];
  __shared__ __attribute__((aligned(16))) ush sM  [4][16*MSTRIDE];

  const float del = DENSEB ? DELTA : DELTA_L1;
  int tid = threadIdx.x, lane = tid & 63, wave = tid >> 6;
  int l15 = lane & 15, quad = lane >> 4;
  int rowblk = blockIdx.x >> 2, split = blockIdx.x & 3;
  int row0 = rowblk * BM + wave * 16;
  int col0 = split * CCHUNK;

  short8 bEnh[4], bEnl[4], bQ[4];
  #pragma unroll
  for (int kf = 0; kf < 4; kf++){
    int go = (row0 + l15)*DD + kf*32 + quad*8;
    bEnh[kf] = *(const short8*)&Enh[go];
    if (DENSEB){
      bEnl[kf] = *(const short8*)&Enl[go];
      bQ[kf] = *(const short8*)&Qh[go];
    }
  }

  f32x4 accN[8], accB[DENSEB ? 8 : 1];
  #pragma unroll
  for (int nf = 0; nf < 8; nf++){ f32x4 z = {0.f,0.f,0.f,0.f}; accN[nf]=z; }
  if (DENSEB){
    #pragma unroll
    for (int nf = 0; nf < 8; nf++){ f32x4 z = {0.f,0.f,0.f,0.f}; accB[nf]=z; }
  }
  float cnL = 0.f, dbL = 0.f;

  int f0 = tid >> 2,        n0 = (tid & 3)*8;
  int f1 = (tid+256) >> 2,  n1 = ((tid+256) & 3)*8;
  uint4 pEh0, pEh1, pVh0, pVh1;
  {
    size_t g0 = (size_t)f0*NN + col0 + n0, g1 = (size_t)f1*NN + col0 + n1;
    pEh0 = *(const uint4*)&EhiT[g0]; pEh1 = *(const uint4*)&EhiT[g1];
    if (DENSEB){
      pVh0 = *(const uint4*)&VhT [g0]; pVh1 = *(const uint4*)&VhT [g1];
    }
  }
  int rr0 = tid >> 4,       ro0 = (tid & 15)*8;
  int rr1 = (tid+256) >> 4, ro1 = ((tid+256) & 15)*8;

  for (int t = 0; t < NTILES; t++){
    int c0 = col0 + t*BN;
    __syncthreads();
    *(uint4*)&sE2[f0*FSTRIDE + n0] = pEh0;  *(uint4*)&sE2[f1*FSTRIDE + n1] = pEh1;
    if (DENSEB){
      *(uint4*)&sV2[f0*FSTRIDE + n0] = pVh0;  *(uint4*)&sV2[f1*FSTRIDE + n1] = pVh1;
    }
    {
      uint4 a0 = *(const uint4*)&Enh[(c0 + rr0)*DD + ro0];
      uint4 a1 = *(const uint4*)&Enh[(c0 + rr1)*DD + ro1];
      *(uint4*)&sEnh[rr0*RSTRIDE + ro0] = a0;  *(uint4*)&sEnh[rr1*RSTRIDE + ro1] = a1;
      if (DENSEB){
        uint4 b0 = *(const uint4*)&Enl[(c0 + rr0)*DD + ro0];
        uint4 b1 = *(const uint4*)&Enl[(c0 + rr1)*DD + ro1];
        uint4 k0 = *(const uint4*)&Kh [(c0 + rr0)*DD + ro0];
        uint4 k1 = *(const uint4*)&Kh [(c0 + rr1)*DD + ro1];
        *(uint4*)&sEnl[rr0*RSTRIDE + ro0] = b0;  *(uint4*)&sEnl[rr1*RSTRIDE + ro1] = b1;
        *(uint4*)&sKh [rr0*RSTRIDE + ro0] = k0;  *(uint4*)&sKh [rr1*RSTRIDE + ro1] = k1;
      }
    }
    __syncthreads();
    if (t + 1 < NTILES){
      int c1 = c0 + BN;
      size_t g0 = (size_t)f0*NN + c1 + n0, g1 = (size_t)f1*NN + c1 + n1;
      pEh0 = *(const uint4*)&EhiT[g0]; pEh1 = *(const uint4*)&EhiT[g1];
      if (DENSEB){
        pVh0 = *(const uint4*)&VhT [g0]; pVh1 = *(const uint4*)&VhT [g1];
      }
    }
    unsigned aw = adjw[(row0 + l15)*256 + (c0 >> 5)];

    f32x4 simT[2], svT[2];
    { f32x4 z = {0.f,0.f,0.f,0.f}; simT[0]=z; simT[1]=z; svT[0]=z; svT[1]=z; }
    #pragma unroll
    for (int f = 0; f < 2; f++){
      #pragma unroll
      for (int kf = 0; kf < 4; kf++){
        int la = (f*16 + l15)*RSTRIDE + kf*32 + quad*8;
        short8 ch = *(const short8*)&sEnh[la];
        simT[f] = __builtin_amdgcn_mfma_f32_16x16x32_bf16(ch, bEnh[kf], simT[f],0,0,0);
        if (DENSEB){
          short8 cl = *(const short8*)&sEnl[la];
          short8 ck = *(const short8*)&sKh [la];
          simT[f] = __builtin_amdgcn_mfma_f32_16x16x32_bf16(cl, bEnh[kf], simT[f],0,0,0);
          simT[f] = __builtin_amdgcn_mfma_f32_16x16x32_bf16(ch, bEnl[kf], simT[f],0,0,0);
          svT [f] = __builtin_amdgcn_mfma_f32_16x16x32_bf16(ck, bQ  [kf], svT [f],0,0,0);
        }
      }
    }
    ushort4 ehv[2];
    unsigned flagb = 0, spb = 0;
    #pragma unroll
    for (int f = 0; f < 2; f++){
      ush vn2[4], veh[4];
      #pragma unroll
      for (int r = 0; r < 4; r++){
        int cbit = f*16 + quad*4 + r;
        bool nbr = (aw >> cbit) & 1u;
        float c = simT[f][r];
        bool pos = nbr && (c >= ALPHA);
        bool neg = nbr && (c <= BETA);
        bool bnd = nbr && !pos && !neg;
        vn2[r] = neg ? (ush)0x3F80 : (ush)0;
        cnL += neg ? 1.f : 0.f;
        if (DENSEB){
          float e = bnd ? __expf(svT[f][r]) : 0.f;
          veh[r] = f2bf(e);
          dbL += e;
        }
        if (nbr && (fabsf(c - ALPHA) < del || fabsf(c - BETA) < del))
          flagb |= 1u << (f*4 + r);
        if (pos || (!DENSEB && bnd))
          spb |= 1u << (f*4 + r);
      }
      int mb = l15*MSTRIDE + f*16 + quad*4;
      *(ushort4*)&sM[wave][mb] = make_ushort4(vn2[0],vn2[1],vn2[2],vn2[3]);
      if (DENSEB)
        ehv[f] = make_ushort4(veh[0],veh[1],veh[2],veh[3]);
    }
    if (__ballot((flagb | spb) != 0)){
      #pragma unroll
      for (int f = 0; f < 2; f++){
        #pragma unroll
        for (int r = 0; r < 4; r++){
          int bit = f*4 + r;
          bool fl = (flagb >> bit) & 1u;
          unsigned long long bm = __ballot(fl);
          if (bm){
            int leader = __ffsll((long long)bm) - 1;
            int base = 0;
            if (lane == leader) base = atomicAdd(flagCnt, __popcll(bm));
            base = __shfl(base, leader, 64);
            if (fl){
              int id = base + __popcll(bm & ((1ull << lane) - 1ull));
              if (id < FLAGCAP){
                float4 rec;
                rec.x = __int_as_float(row0 + l15);
                rec.y = __int_as_float(c0 + f*16 + quad*4 + r);
                rec.z = simT[f][r];
                rec.w = DENSEB ? svT[f][r] : 0.f;
                flags[id] = rec;
              }
            }
          }
          bool f2 = (spb >> bit) & 1u;
          unsigned long long bm2 = __ballot(f2);
          if (bm2){
            int leader = __ffsll((long long)bm2) - 1;
            int base = 0;
            if (lane == leader) base = atomicAdd(flag2Cnt, __popcll(bm2));
            base = __shfl(base, leader, 64);
            if (f2){
              int id = base + __popcll(bm2 & ((1ull << lane) - 1ull));
              if (id < FLAG2CAP){
                float c = simT[f][r];
                int j = c0 + f*16 + quad*4 + r;
                int cls = (c >= ALPHA) ? 0 : 1;
                float4 rec;
                rec.x = __int_as_float(row0 + l15);
                rec.y = __int_as_float(j | (cls << 16));
                rec.z = c;
                rec.w = DENSEB ? svT[f][r] : 0.f;
                flags2[id] = rec;
              }
            }
          }
        }
      }
    }
    {
      short8 mNeg = *(const short8*)&sM[wave][l15*MSTRIDE + quad*8];
      #pragma unroll
      for (int nf = 0; nf < 8; nf++){
        int so = (nf*16 + l15)*FSTRIDE + quad*8;
        short8 eth = *(const short8*)&sE2[so];
        accN[nf] = __builtin_amdgcn_mfma_f32_16x16x32_bf16(mNeg, eth, accN[nf],0,0,0);
      }
    }
    if (DENSEB){
      int mb0 = l15*MSTRIDE + quad*4;
      *(ushort4*)&sM[wave][mb0]      = ehv[0];
      *(ushort4*)&sM[wave][mb0 + 16] = ehv[1];
      short8 mEh = *(const short8*)&sM[wave][l15*MSTRIDE + quad*8];
      #pragma unroll
      for (int nf = 0; nf < 8; nf++){
        int so = (nf*16 + l15)*FSTRIDE + quad*8;
        short8 vth = *(const short8*)&sV2[so];
        accB[nf] = __builtin_amdgcn_mfma_f32_16x16x32_bf16(mEh, vth, accB[nf],0,0,0);
      }
    }
  }
  #pragma unroll
  for (int nf = 0; nf < 8; nf++){
    int col = nf*16 + l15;
    #pragma unroll
    for (int r = 0; r < 4; r++){
      int row = row0 + quad*4 + r;
      atomicAdd(&Nsum[row*DD + col], accN[nf][r]);
      if (DENSEB) atomicAdd(&Bsum[row*DD + col], accB[nf][r]);
    }
  }
  cnL += __shfl_xor(cnL, 16, 64); cnL += __shfl_xor(cnL, 32, 64);
  if (DENSEB){ dbL += __shfl_xor(dbL, 16, 64); dbL += __shfl_xor(dbL, 32, 64); }
  if (quad == 0){
    atomicAdd(&cntN[row0 + l15], cnL);
    if (DENSEB) atomicAdd(&denB[row0 + l15], dbL);
  }
}

// ---------------- merged sparse replay + fp64 refine (commuting atomics) ----------------
// Class-dependent formulas (mirror the dense paths exactly):
//   neg (dense, both layers): ev_neg = hi-only
//   pos (sparse, both layers): ev_pos = hi+lo
//   bnd L1 (dotmode=1, sparse): bv = ehf*vh + (elf*vh + ehf*vl)  (3-term)
//   bnd L2 (dotmode=0, dense):  bv = ehf*vh                      (1-term)
__global__ void k_fix(const float* __restrict__ E, const double* __restrict__ nrm64,
    const ush* __restrict__ EhiT, const ush* __restrict__ EloT,
    const ush* __restrict__ VhT,  const ush* __restrict__ VloT,
    const ush* __restrict__ Qh,   const ush* __restrict__ Kh, int dotmode,
    const int* __restrict__ flag2Cnt, const float4* __restrict__ flags2,
    const int* __restrict__ flagCnt,  const float4* __restrict__ flags,
    float* __restrict__ Psum, float* __restrict__ Nsum, float* __restrict__ Bsum,
    float* __restrict__ cntP, float* __restrict__ cntN, float* __restrict__ denB)
{
  int lane = threadIdx.x & 63;
  if (blockIdx.x < 256){
    // ---- sparse pos/bnd replay ----
    int cnt = *flag2Cnt; if (cnt > FLAG2CAP) cnt = FLAG2CAP;
    int gw = (blockIdx.x * blockDim.x + threadIdx.x) >> 6;
    int nw = (256 * blockDim.x) >> 6;
    for (int idx = gw; idx < cnt; idx += nw){
      float4 rec = flags2[idx];
      int i = __float_as_int(rec.x);
      int jraw = __float_as_int(rec.y);
      int j = jraw & 0xFFFF, cls = jraw >> 16;
      if (cls == 0){
        #pragma unroll
        for (int h = 0; h < 2; h++){
          int d = lane + h*64;
          float ev = bf2f(EhiT[(size_t)d*NN + j]) + bf2f(EloT[(size_t)d*NN + j]);
          atomicAdd(&Psum[i*DD + d], ev);
        }
        if (lane == 0) atomicAdd(&cntP[i], 1.f);
      } else {
        float s = dotmode ? qkdot(Qh, Kh, i, j, lane) : rec.w;
        float e = __expf(s);
        float ehf = bf2f(f2bf(e));
        float elf = bf2f(f2bf(e - ehf));
        #pragma unroll
        for (int h = 0; h < 2; h++){
          int d = lane + h*64;
          float vh = bf2f(VhT [(size_t)d*NN + j]);
          float bv = ehf*vh;
          if (dotmode) bv += elf*vh + ehf*bf2f(VloT[(size_t)d*NN + j]);
          atomicAdd(&Bsum[i*DD + d], bv);
        }
        if (lane == 0) atomicAdd(&denB[i], e);
      }
    }
  } else {
    // ---- fp64 boundary refinement ----
    int cnt = *flagCnt; if (cnt > FLAGCAP) cnt = FLAGCAP;
    int gw = ((blockIdx.x - 256) * blockDim.x + threadIdx.x) >> 6;
    int nw = (512 * blockDim.x) >> 6;
    for (int idx = gw; idx < cnt; idx += nw){
      float4 rec = flags[idx];
      int i = __float_as_int(rec.x), j = __float_as_int(rec.y);
      float c = rec.z;
      float ei0 = E[i*DD + lane], ei1 = E[i*DD + 64 + lane];
      float ej0 = E[j*DD + lane], ej1 = E[j*DD + 64 + lane];
      double d = (double)ei0*(double)ej0 + (double)ei1*(double)ej1;
      #pragma unroll
      for (int m = 32; m; m >>= 1) d += __shfl_xor(d, m, 64);
      double se = d / (nrm64[i]*nrm64[j]);
      int ce = (se >= (double)ALPHA) ? 0 : ((se <= (double)BETA) ? 1 : 2);
      int cc = (c >= ALPHA) ? 0 : ((c <= BETA) ? 1 : 2);
      if (ce == cc) continue;
      float s = dotmode ? qkdot(Qh, Kh, i, j, lane) : rec.w;
      float e = __expf(s);
      float ehf = bf2f(f2bf(e));
      float elf = bf2f(f2bf(e - ehf));
      #pragma unroll
      for (int h = 0; h < 2; h++){
        int dd2 = lane + h*64;
        float evh = bf2f(EhiT[(size_t)dd2*NN + j]);
        float evp = evh + bf2f(EloT[(size_t)dd2*NN + j]);  // pos: hi+lo
        float vh = bf2f(VhT[(size_t)dd2*NN + j]);
        float bv = ehf*vh;
        if (dotmode) bv += elf*vh + ehf*bf2f(VloT[(size_t)dd2*NN + j]);
        float subv = (cc==0) ? -evp : (cc==1) ? -evh : -bv;
        float* subA = (cc==0) ? Psum : (cc==1) ? Nsum : Bsum;
        atomicAdd(&subA[i*DD + dd2], subv);
        float addv = (ce==0) ? evp : (ce==1) ? evh : bv;
        float* addA = (ce==0) ? Psum : (ce==1) ? Nsum : Bsum;
        atomicAdd(&addA[i*DD + dd2], addv);
      }
      if (lane == 0){
        float* subC = (cc==0) ? cntP : (cc==1) ? cntN : denB;
        atomicAdd(&subC[i], (cc==2) ? -e : -1.f);
        float* addC = (ce==0) ? cntP : (ce==1) ? cntN : denB;
        atomicAdd(&addC[i], (ce==2) ?  e :  1.f);
      }
    }
  }
}

extern "C" void kernel_launch(void* const* d_in, const int* in_sizes, int n_in,
                              void* d_out, int out_size, void* d_ws, size_t ws_size,
                              hipStream_t stream){
  const float* adj   = (const float*)d_in[0];
  const float* embed = (const float*)d_in[1];
  const float* gc_w  = (const float*)d_in[2];
  const float* gc_b  = (const float*)d_in[3];
  const float* wq = (const float*)d_in[4];
  const float* bq = (const float*)d_in[5];
  const float* wk = (const float*)d_in[6];
  const float* bk = (const float*)d_in[7];
  const float* wv = (const float*)d_in[8];
  const float* bv = (const float*)d_in[9];
  const float* g1w = (const float*)d_in[10];
  const float* g1b = (const float*)d_in[11];
  const float* g2w = (const float*)d_in[12];
  const float* g2b = (const float*)d_in[13];
  const float* lw  = (const float*)d_in[14];
  float* out = (float*)d_out;

  char* p = (char*)d_ws;
  auto alloc = [&](size_t bytes)->void*{ void* r = (void*)p; p += (bytes + 255) & ~(size_t)255; return r; };
  ush* qkvTh = (ush*)alloc(384*128*2);  ush* qkvTl = (ush*)alloc(384*128*2);
  ush* g1wTh = (ush*)alloc(512*256*2);  ush* g1wTl = (ush*)alloc(512*256*2);
  ush* gcwTh = (ush*)alloc(2*128*128*2); ush* gcwTl = (ush*)alloc(2*128*128*2);
  unsigned* adjw = (unsigned*)alloc((size_t)NN*256*4);
  double* nrm64 = (double*)alloc(NN*8);
  ush* Enh  = (ush*)alloc((size_t)NN*DD*2);
  ush* Enl  = (ush*)alloc((size_t)NN*DD*2);
  ush* EhiT = (ush*)alloc((size_t)NN*DD*2);
  ush* EloT = (ush*)alloc((size_t)NN*DD*2);
  ush* Qh   = (ush*)alloc((size_t)NN*DD*2);
  ush* Khb  = (ush*)alloc((size_t)NN*DD*2);
  ush* VhT  = (ush*)alloc((size_t)NN*DD*2);
  ush* VloT = (ush*)alloc((size_t)NN*DD*2);
  char* zbase = p;
  float* Psum = (float*)alloc((size_t)NN*DD*4);
  float* Nsum = (float*)alloc((size_t)NN*DD*4);
  float* Bsum = (float*)alloc((size_t)NN*DD*4);
  float* cntP = (float*)alloc(NN*4);
  float* cntN = (float*)alloc(NN*4);
  float* denB = (float*)alloc(NN*4);
  int*   flagCnt  = (int*)alloc(256);
  int*   flag2Cnt = (int*)alloc(256);
  size_t zbytes = (size_t)(p - zbase);
  float4* flags  = (float4*)alloc((size_t)FLAGCAP*16);
  float4* flags2 = (float4*)alloc((size_t)FLAG2CAP*16);
  float* cur0 = (float*)alloc((size_t)NN*DD*4);

  // one-time prep (per call; inputs restored each replay)
  k_init<<<NN + 832, 256, 0, stream>>>(adj, adjw, wq, wk, wv, g1w, gc_w,
      qkvTh, qkvTl, g1wTh, g1wTl, gcwTh, gcwTl);

  const float* Ecur = embed;
  for (int l = 0; l < 2; l++){
    k_prep<<<2816, 256, 0, stream>>>(Ecur, nrm64, Enh, Enl, EhiT, EloT,
        qkvTh, qkvTl, bq, bk, bv, Qh, Khb, VhT, VloT);
    hipMemsetAsync(zbase, 0, zbytes, stream);
    if (l == 0)
      k_fused<0><<<(NN/BM)*CSPLIT, 256, 0, stream>>>(adjw, Enh, Enl, Qh, Khb,
          EhiT, EloT, VhT, VloT, Nsum, Bsum, cntN, denB,
          flagCnt, flags, flag2Cnt, flags2);
    else
      k_fused<1><<<(NN/BM)*CSPLIT, 256, 0, stream>>>(adjw, Enh, Enl, Qh, Khb,
          EhiT, EloT, VhT, VloT, Nsum, Bsum, cntN, denB,
          flagCnt, flags, flag2Cnt, flags2);
    k_fix<<<768, 256, 0, stream>>>(Ecur, nrm64, EhiT, EloT, VhT, VloT,
        Qh, Khb, (l == 0) ? 1 : 0, flag2Cnt, flags2, flagCnt, flags,
        Psum, Nsum, Bsum, cntP, cntN, denB);
    k_mlp<<<512, 256, 0, stream>>>(Ecur, Psum, Bsum, Nsum, cntP, cntN, denB,
        g1wTh, g1wTl, g1b, g2w, g2b,
        gcwTh + l*128*128, gcwTl + l*128*128, gc_b + l*128,
        cur0, lw, l, (l == 0) ? cur0 : out);
    Ecur = (l == 0) ? cur0 : out;
  }
}